// Round 8
// baseline (831.592 us; speedup 1.0000x reference)
//
#include <hip/hip_runtime.h>
#include <hip/hip_bf16.h>

// ---------------- problem constants ----------------
#define NLAY 4
#define DH   512
#define NST  64
#define NB   16
#define SL   2048
#define NDO  256
#define BL   (NB*SL)      // 32768 rows
#define KDIM 512
#define TWOPI 6.283185307179586476925287

typedef unsigned short u16;
typedef __attribute__((ext_vector_type(8))) short  short8v;   // 8 bf16 (4 VGPR) MFMA frag
typedef __attribute__((ext_vector_type(8))) unsigned short ushort8v;
typedef __attribute__((ext_vector_type(4))) float  f32x4;

#define RCPF(x) __builtin_amdgcn_rcpf(x)

// ---------------- small helpers ----------------
__device__ __forceinline__ float bf2f(u16 v){
  union { unsigned u; float f; } x; x.u = ((unsigned)v) << 16; return x.f;
}
__device__ __forceinline__ u16 f2bf(float f){
  union { float f; unsigned u; } x; x.f = f;
  unsigned u = x.u;
  unsigned r = u + 0x7fffu + ((u >> 16) & 1u);   // RNE
  return (u16)(r >> 16);
}
__device__ __forceinline__ void cmulw(float& xr, float& xi, float wr, float wi){
  float tr = xr*wr - xi*wi;
  xi = fmaf(xr, wi, xi*wr);
  xr = tr;
}
__device__ __forceinline__ float gelu_fast(float v){
  const float c0 = 0.7978845608028654f;
  float u = c0 * fmaf(0.044715f, v*v*v, v);
  return v * RCPF(1.0f + __expf(-2.0f * u));
}
// async global(16B/lane) -> LDS (wave-uniform base + lane*16, HW-linear)
__device__ __forceinline__ void gload16(const void* g, void* l){
  __builtin_amdgcn_global_load_lds(
      (__attribute__((address_space(1))) void*)(g),
      (__attribute__((address_space(3))) void*)(l), 16, 0, 0);
}

// ---------------- DFT-16 in registers (radix-4 x radix-4), natural in/out ----
template<int SGN>
__device__ __forceinline__ void dft4w(float& r0, float& i0, float& r1, float& i1,
                                      float& r2, float& i2, float& r3, float& i3){
  const float t0r = r0 + r2, t0i = i0 + i2;
  const float t1r = r0 - r2, t1i = i0 - i2;
  const float t2r = r1 + r3, t2i = i1 + i3;
  const float t3r = r1 - r3, t3i = i1 - i3;
  r0 = t0r + t2r; i0 = t0i + t2i;
  r2 = t0r - t2r; i2 = t0i - t2i;
  if (SGN < 0){ r1 = t1r + t3i; i1 = t1i - t3r; r3 = t1r - t3i; i3 = t1i + t3r; }
  else        { r1 = t1r - t3i; i1 = t1i + t3r; r3 = t1r + t3i; i3 = t1i - t3r; }
}

template<int SGN>
__device__ __forceinline__ void dft16(float* re, float* im){
#pragma unroll
  for (int b = 0; b < 4; b++)
    dft4w<SGN>(re[b], im[b], re[4+b], im[4+b], re[8+b], im[8+b], re[12+b], im[12+b]);
  const float C1 = 0.92387953251128675613f, S1_ = 0.38268343236508977172f;
  const float C2 = 0.70710678118654752440f;
  const float sg = (SGN < 0) ? -1.f : 1.f;
  cmulw(re[5],  im[5],   C1,  sg*S1_);
  cmulw(re[9],  im[9],   C2,  sg*C2);
  cmulw(re[13], im[13],  S1_, sg*C1);
  cmulw(re[6],  im[6],   C2,  sg*C2);
  cmulw(re[10], im[10],  0.f, sg*1.f);
  cmulw(re[14], im[14], -C2,  sg*C2);
  cmulw(re[7],  im[7],   S1_, sg*C1);
  cmulw(re[11], im[11], -C2,  sg*C2);
  cmulw(re[15], im[15], -C1,  sg*(-S1_));
#pragma unroll
  for (int c = 0; c < 4; c++)
    dft4w<SGN>(re[4*c], im[4*c], re[4*c+1], im[4*c+1], re[4*c+2], im[4*c+2], re[4*c+3], im[4*c+3]);
  float tr_, ti_;
#define SWP(A,B) tr_=re[A]; re[A]=re[B]; re[B]=tr_; ti_=im[A]; im[A]=im[B]; im[B]=ti_;
  SWP(1,4) SWP(2,8) SWP(3,12) SWP(6,9) SWP(7,13) SWP(11,14)
#undef SWP
}

// LDS padding: all three stage patterns <=2-way bank conflicts
__device__ __forceinline__ int cxpad(int i){ return i + (i >> 4) + ((i >> 8) << 1); }
#define CXSZ 4384

// forward 4096-pt DIF radix-16 (float2 LDS, 2 barriers per exchange)
__device__ __forceinline__ void fwd4096(float* re, float* im, float2* cx, int t){
  dft16<-1>(re, im);
  const float a0 = -(float)(TWOPI/4096.0) * (float)t;
#pragma unroll
  for (int k = 0; k < 16; k++){
    if (k){ float sn = __sinf(a0*(float)k), cs = __cosf(a0*(float)k); cmulw(re[k], im[k], cs, sn); }
    cx[cxpad(t + 256*k)] = make_float2(re[k], im[k]);
  }
  __syncthreads();
  const int k1 = t >> 4, m2 = t & 15;
  const int b2 = k1*256 + m2;
#pragma unroll
  for (int j = 0; j < 16; j++){ float2 v = cx[cxpad(b2 + 16*j)]; re[j] = v.x; im[j] = v.y; }
  dft16<-1>(re, im);
  const float b0 = -(float)(TWOPI/256.0) * (float)m2;
  __syncthreads();
#pragma unroll
  for (int k = 0; k < 16; k++){
    if (k){ float sn = __sinf(b0*(float)k), cs = __cosf(b0*(float)k); cmulw(re[k], im[k], cs, sn); }
    cx[cxpad(b2 + 16*k)] = make_float2(re[k], im[k]);
  }
  __syncthreads();
#pragma unroll
  for (int j = 0; j < 16; j++){ float2 v = cx[cxpad(16*t + j)]; re[j] = v.x; im[j] = v.y; }
  dft16<-1>(re, im);
}

// inverse: input = values at positions 16t+k3, output time y[t+256j] (unscaled)
__device__ __forceinline__ void inv4096(float* re, float* im, float2* cx, int t){
  dft16<1>(re, im);
#pragma unroll
  for (int j = 0; j < 16; j++) cx[cxpad(16*t + j)] = make_float2(re[j], im[j]);
  __syncthreads();
  const int k1 = t >> 4, m2 = t & 15;
  const int b2 = k1*256 + m2;
  const float b0 = (float)(TWOPI/256.0) * (float)m2;
#pragma unroll
  for (int k = 0; k < 16; k++){
    float2 v = cx[cxpad(b2 + 16*k)];
    re[k] = v.x; im[k] = v.y;
    if (k){ float sn = __sinf(b0*(float)k), cs = __cosf(b0*(float)k); cmulw(re[k], im[k], cs, sn); }
  }
  dft16<1>(re, im);
  __syncthreads();
#pragma unroll
  for (int j = 0; j < 16; j++) cx[cxpad(b2 + 16*j)] = make_float2(re[j], im[j]);
  __syncthreads();
  const float a0 = (float)(TWOPI/4096.0) * (float)t;
#pragma unroll
  for (int k = 0; k < 16; k++){
    float2 v = cx[cxpad(t + 256*k)];
    re[k] = v.x; im[k] = v.y;
    if (k){ float sn = __sinf(a0*(float)k), cs = __cosf(a0*(float)k); cmulw(re[k], im[k], cs, sn); }
  }
  dft16<1>(re, im);
}

// ---------------- prep: per-(lay,h,n) Woodbury weights ----------------
__global__ __launch_bounds__(256) void prep_k(
  const float* __restrict__ lam_re, const float* __restrict__ lam_im,
  const float* __restrict__ p_re,  const float* __restrict__ p_im,
  const float* __restrict__ b_re,  const float* __restrict__ b_im,
  const float* __restrict__ c_re,  const float* __restrict__ c_im,
  float4* __restrict__ cwA, float4* __restrict__ cwB, float* __restrict__ cwS)
{
  const int i = blockIdx.x * 256 + threadIdx.x;   // < NLAY*DH*NST
  const float lr = lam_re[i], li = lam_im[i];
  const float pr = p_re[i],  pi = p_im[i];
  const float br = b_re[i],  bi = b_im[i];
  const float cr = c_re[i],  ci = c_im[i];
  cwA[i] = make_float4(lr, li, cr*br + ci*bi, cr*bi - ci*br);                  // Lam, conj(C)*B
  cwB[i] = make_float4(cr*pr + ci*pi, cr*pi - ci*pr, pr*br + pi*bi, pr*bi - pi*br); // cC*P, cP*B
  cwS[i] = pr*pr + pi*pi;                                                      // conj(P)*P (real)
}

// ---------------- Cauchy/Woodbury generating function -> at_roots -----------
// g = i*gi with gi = (2/step)*tan(theta/2);  c = 1 + i*tan(theta/2).
__global__ __launch_bounds__(256, 2) void cauchy_k(
    const float4* __restrict__ cwA, const float4* __restrict__ cwB,
    const float* __restrict__ cwS, const float* __restrict__ lstep,
    float2* __restrict__ Kd)
{
  const int t = threadIdx.x;
  const int h = blockIdx.y, lay = blockIdx.z;
  const int lb = blockIdx.x * 256 + t;
  const int wb = (lay*DH + h) * NST;
  const float tw0 = 2.0f * expf(-lstep[lay*DH + h]);   // 2/step

  float T0,T1,T2,T3, g0,g1,g2,g3;
  { float sn, cs;
    sincosf((float)(TWOPI/4096.0)*(float)(lb       ), &sn, &cs); T0 = sn*RCPF(cs); g0 = tw0*T0;
    sincosf((float)(TWOPI/4096.0)*(float)(lb +  512), &sn, &cs); T1 = sn*RCPF(cs); g1 = tw0*T1;
    sincosf((float)(TWOPI/4096.0)*(float)(lb + 1024), &sn, &cs); T2 = sn*RCPF(cs); g2 = tw0*T2;
    sincosf((float)(TWOPI/4096.0)*(float)(lb + 1536), &sn, &cs); T3 = sn*RCPF(cs); g3 = tw0*T3;
  }

  float k00r0=0,k00i0=0,k01r0=0,k01i0=0,k10r0=0,k10i0=0,k11r0=0,k11i0=0;
  float k00r1=0,k00i1=0,k01r1=0,k01i1=0,k10r1=0,k10i1=0,k11r1=0,k11i1=0;
  float k00r2=0,k00i2=0,k01r2=0,k01i2=0,k10r2=0,k10i2=0,k11r2=0,k11i2=0;
  float k00r3=0,k00i3=0,k01r3=0,k01i3=0,k10r3=0,k10i3=0,k11r3=0,k11i3=0;

#pragma unroll 2
  for (int n = 0; n < NST; n++){
    const float4 A  = cwA[wb + n];
    const float4 Bv = cwB[wb + n];
    const float w11 = cwS[wb + n];
    const float nlr = -A.x;            // -lam_re  (real part of g - Lam)
    const float dr2 = A.x * A.x;
#define CSTEP(J) { \
    const float di = g##J - A.y; \
    const float sI = RCPF(fmaf(di, di, dr2)); \
    const float ivr = nlr * sI, ivi = -di * sI; \
    k00r##J = fmaf(A.z,  ivr, fmaf(-A.w,  ivi, k00r##J)); \
    k00i##J = fmaf(A.z,  ivi, fmaf( A.w,  ivr, k00i##J)); \
    k01r##J = fmaf(Bv.x, ivr, fmaf(-Bv.y, ivi, k01r##J)); \
    k01i##J = fmaf(Bv.x, ivi, fmaf( Bv.y, ivr, k01i##J)); \
    k10r##J = fmaf(Bv.z, ivr, fmaf(-Bv.w, ivi, k10r##J)); \
    k10i##J = fmaf(Bv.z, ivi, fmaf( Bv.w, ivr, k10i##J)); \
    k11r##J = fmaf(w11,  ivr, k11r##J); \
    k11i##J = fmaf(w11,  ivi, k11i##J); }
    CSTEP(0) CSTEP(1) CSTEP(2) CSTEP(3)
#undef CSTEP
  }

  float2* kp = Kd + (size_t)(lay*DH + h) * 4096;
#define COUT(J, LOFF) { \
    const float d1r = 1.f + k11r##J, d1i = k11i##J; \
    const float idn = RCPF(fmaf(d1r, d1r, d1i*d1i)); \
    const float wr = k01r##J*k10r##J - k01i##J*k10i##J; \
    const float wi = k01r##J*k10i##J + k01i##J*k10r##J; \
    const float vr = fmaf(wr, d1r,  wi*d1i) * idn; \
    const float vi = fmaf(wi, d1r, -wr*d1i) * idn; \
    const float sr = k00r##J - vr, si = k00i##J - vi; \
    kp[lb + LOFF] = make_float2(fmaf(-T##J, si, sr), fmaf(T##J, sr, si)); }
  COUT(0, 0) COUT(1, 512) COUT(2, 1024) COUT(3, 1536)
#undef COUT
}

// ---------------- ifft2048 + fwd fft4096 -> Kd (digit-rev order) -------------
__global__ __launch_bounds__(256) void kdfft_k(float2* __restrict__ Kd){
  __shared__ float  ar[SL], ai[SL];
  __shared__ float2 cx[CXSZ];
  const int t = threadIdx.x;
  const size_t base = (size_t)blockIdx.x * 4096;
#pragma unroll
  for (int q = 0; q < 8; q++){
    const int l = t + 256*q;
    float2 v = Kd[base + l];
    const int brv = __brev((unsigned)l) >> 21;    // 11-bit reverse
    ar[brv] = v.x; ai[brv] = v.y;
  }
  __syncthreads();

  // inverse DFT-2048 (radix-2 DIT, bit-reversed input -> natural K)
  for (int s = 0; s < 11; s++){
    const int half = 1 << s;
    const float fac = (float)(TWOPI) / (float)(2 << s);
#pragma unroll
    for (int q = 0; q < 4; q++){
      const int v = t + 256*q;
      const int pos = v & (half - 1);
      const int i0 = ((v >> s) << (s+1)) + pos;
      const int i1 = i0 + half;
      const float ang = fac * (float)pos;
      const float wc = __cosf(ang), ws = __sinf(ang);   // e^{+i ang}
      const float xr = ar[i1], xi = ai[i1];
      const float tr = wc*xr - ws*xi, ti = fmaf(wc, xi, ws*xr);
      const float ur_ = ar[i0], ui_ = ai[i0];
      ar[i0] = ur_ + tr; ai[i0] = ui_ + ti;
      ar[i1] = ur_ - tr; ai[i1] = ui_ - ti;
    }
    __syncthreads();
  }

  // K (real, scaled 1/2048), zero-pad to 4096, forward DIF -> Kd
  float re[16], im[16];
#pragma unroll
  for (int j = 0; j < 16; j++){
    re[j] = (j < 8) ? ar[t + 256*j] * (1.0f/2048.f) : 0.f;
    im[j] = 0.f;
  }
  fwd4096(re, im, cx, t);
  float2* kp = Kd + base + 16*t;
#pragma unroll
  for (int k = 0; k < 16; k += 2)
    *(float4*)(kp + k) = make_float4(re[k], im[k], re[k+1], im[k+1]);
}

// ---------------- weight convert+transpose f32[K][N] -> bf16[N][K] -----------
__global__ __launch_bounds__(256) void wconv_k(const float* __restrict__ src,
    u16* __restrict__ dst, int K, int N){
  __shared__ u16 tile[64][72];
  const size_t mb = (size_t)blockIdx.z * K * N;
  const int k0 = blockIdx.x * 64, n0 = blockIdx.y * 64;
  const int r = threadIdx.x >> 2, c4 = (threadIdx.x & 3) * 16;
  const float* s = src + mb + (size_t)(k0 + r) * N + n0 + c4;
  float4 f0 = *(const float4*)s, f1 = *(const float4*)(s+4);
  float4 f2 = *(const float4*)(s+8), f3 = *(const float4*)(s+12);
  tile[c4+0][r]=f2bf(f0.x); tile[c4+1][r]=f2bf(f0.y); tile[c4+2][r]=f2bf(f0.z); tile[c4+3][r]=f2bf(f0.w);
  tile[c4+4][r]=f2bf(f1.x); tile[c4+5][r]=f2bf(f1.y); tile[c4+6][r]=f2bf(f1.z); tile[c4+7][r]=f2bf(f1.w);
  tile[c4+8][r]=f2bf(f2.x); tile[c4+9][r]=f2bf(f2.y); tile[c4+10][r]=f2bf(f2.z); tile[c4+11][r]=f2bf(f2.w);
  tile[c4+12][r]=f2bf(f3.x); tile[c4+13][r]=f2bf(f3.y); tile[c4+14][r]=f2bf(f3.z); tile[c4+15][r]=f2bf(f3.w);
  __syncthreads();
  u16* d = dst + mb + (size_t)(n0 + r) * K + k0 + c4;
  *(ushort8v*)d       = *(const ushort8v*)&tile[r][c4];
  *(ushort8v*)(d + 8) = *(const ushort8v*)&tile[r][c4 + 8];
}

// ---------------- fused LayerNorm + transpose: bf16 [b,l,h] -> bf16 [b,h,l] --
#define LTILE 32
__device__ __forceinline__ int lnswz(int h){ return ((h >> 1) + (h >> 6)) & 3; }

__global__ __launch_bounds__(256) void lnt_k(const u16* __restrict__ hsrc,
    const float* __restrict__ gam, const float* __restrict__ bet,
    u16* __restrict__ zT){
  __shared__ u16 tile[DH][LTILE];
  __shared__ float smu[LTILE], srs[LTILE];
  const int t = threadIdx.x;
  const int b = blockIdx.y, l0 = blockIdx.x * LTILE;
  const int r = t >> 3, hb = (t & 7) * 64;
  const u16* p = hsrc + ((size_t)b * SL + l0 + r) * DH + hb;
  float s = 0.f, sq = 0.f;
#pragma unroll
  for (int j8 = 0; j8 < 8; j8++){
    ushort8v w = *(const ushort8v*)(p + j8*8);
    const int h0 = hb + j8*8;
#pragma unroll
    for (int d = 0; d < 8; d++){
      const float f = bf2f((u16)w[d]);
      s += f; sq = fmaf(f, f, sq);
      tile[h0+d][r ^ (lnswz(h0+d) << 3)] = (u16)w[d];
    }
  }
  s  += __shfl_xor(s, 1);  sq += __shfl_xor(sq, 1);
  s  += __shfl_xor(s, 2);  sq += __shfl_xor(sq, 2);
  s  += __shfl_xor(s, 4);  sq += __shfl_xor(sq, 4);
  if ((t & 7) == 0){
    const float mu = s * (1.0f/DH);
    smu[r] = mu;
    srs[r] = rsqrtf(sq * (1.0f/DH) - mu*mu + 1e-6f);
  }
  __syncthreads();

#pragma unroll
  for (int hh = 0; hh < 2; hh++){
    const int h = t + hh*256;
    const float g = gam[h], be = bet[h];
    const int sw = lnswz(h);
    u16* dst = zT + ((size_t)b * DH + h) * SL + l0;
#pragma unroll
    for (int og = 0; og < 4; og++){
      const int lg = og ^ sw;
      ushort8v v = *(const ushort8v*)&tile[h][og*8];
      const float4 m0 = *(const float4*)&smu[lg*8];
      const float4 m1 = *(const float4*)&smu[lg*8 + 4];
      const float4 r0 = *(const float4*)&srs[lg*8];
      const float4 r1 = *(const float4*)&srs[lg*8 + 4];
      ushort8v o;
      o[0] = f2bf(fmaf(bf2f((u16)v[0]) - m0.x, r0.x*g, be));
      o[1] = f2bf(fmaf(bf2f((u16)v[1]) - m0.y, r0.y*g, be));
      o[2] = f2bf(fmaf(bf2f((u16)v[2]) - m0.z, r0.z*g, be));
      o[3] = f2bf(fmaf(bf2f((u16)v[3]) - m0.w, r0.w*g, be));
      o[4] = f2bf(fmaf(bf2f((u16)v[4]) - m1.x, r1.x*g, be));
      o[5] = f2bf(fmaf(bf2f((u16)v[5]) - m1.y, r1.y*g, be));
      o[6] = f2bf(fmaf(bf2f((u16)v[6]) - m1.z, r1.z*g, be));
      o[7] = f2bf(fmaf(bf2f((u16)v[7]) - m1.w, r1.w*g, be));
      *(ushort8v*)(dst + lg*8) = o;
    }
  }
}

// ---------------- S4 FFT convolution + D*u + GELU ----------------------------
__global__ __launch_bounds__(256) void s4conv_k(
    const u16* __restrict__ zT, const float2* __restrict__ Kd,
    const float* __restrict__ dpar, u16* __restrict__ yT)
{
  __shared__ float2 cx[CXSZ];
  const int t = threadIdx.x;
  const int wg = blockIdx.x;          // 8 pairs * 512 channels
  const int h = wg & 511, bp = wg >> 9;
  const u16* r1 = zT + ((size_t)(2*bp) * DH + h) * SL;
  const u16* r2 = r1 + (size_t)DH * SL;
  float ur1[8], ur2[8];
  float re[16], im[16];
#pragma unroll
  for (int j = 0; j < 8; j++){
    ur1[j] = bf2f(r1[t + 256*j]);
    ur2[j] = bf2f(r2[t + 256*j]);
    re[j] = ur1[j]; im[j] = ur2[j];
  }
#pragma unroll
  for (int j = 8; j < 16; j++){ re[j] = 0.f; im[j] = 0.f; }

  fwd4096(re, im, cx, t);

  const float2* kp = Kd + (size_t)h * 4096 + 16*t;
#pragma unroll
  for (int k = 0; k < 16; k += 2){
    float4 w2 = *(const float4*)(kp + k);
    cmulw(re[k],   im[k],   w2.x, w2.y);
    cmulw(re[k+1], im[k+1], w2.z, w2.w);
  }

  inv4096(re, im, cx, t);

  const float Dv = dpar[h];
  u16* y1 = yT + ((size_t)(2*bp) * DH + h) * SL;
  u16* y2 = y1 + (size_t)DH * SL;
#pragma unroll
  for (int j = 0; j < 8; j++){
    float v1 = fmaf(re[j], (1.0f/4096.f), Dv * ur1[j]);
    float v2 = fmaf(im[j], (1.0f/4096.f), Dv * ur2[j]);
    y1[t + 256*j] = f2bf(gelu_fast(v1));
    y2[t + 256*j] = f2bf(gelu_fast(v2));
  }
}

// ---------------- bf16 MFMA GEMM, 128x128 tile, BK=32 ------------------------
// LDS layout: 16B granules, G(r,g) = (r<<2) | ((g ^ r ^ (r>>2)) & 3).
// gload_lds writes are HW-linear; the swizzle lives in the per-lane GLOBAL
// source address (m173) and the fragment ds_read_b128 address (same formula).
// AMODE: 0 = bf16 [M][K] (gload_lds); 1 = bf16 [K][M] batched (manual);
//        2 = f32 [M][K] (reg convert). Wt bf16 [N][K] always gload_lds.
template<int AMODE, bool RESID, bool OUTBF>
__global__ __launch_bounds__(256) void gemm_k(
    const void* __restrict__ Aptr, const u16* __restrict__ Wt,
    const float* __restrict__ bias,
    const u16* __restrict__ resid, void* __restrict__ Coutv,
    int Mb, int N)
{
  __shared__ u16 As[4096];   // 128 rows x 32 k  (512 granules)
  __shared__ u16 Bs[4096];
  const int t = threadIdx.x;
  const int n0 = blockIdx.x * 128, m0 = blockIdx.y * 128, bb = blockIdx.z;
  const int lane = t & 63, wv = t >> 6;
  const int wm = (wv >> 1) * 64, wn = (wv & 1) * 64;
  const int wbase = t & 192;           // wave granule base (w*64)
  f32x4 acc[4][4];
#pragma unroll
  for (int mi = 0; mi < 4; mi++)
#pragma unroll
    for (int ni = 0; ni < 4; ni++) acc[mi][ni] = {0.f, 0.f, 0.f, 0.f};

  const u16*  Ab = (const u16*)Aptr;
  const float* Af = (const float*)Aptr;
  const size_t Abase = (AMODE == 1) ? (size_t)bb * KDIM * Mb : 0;

  for (int k0 = 0; k0 < KDIM; k0 += 32){
    __syncthreads();
    // ---- A staging ----
    if (AMODE == 0){
#pragma unroll
      for (int i = 0; i < 2; i++){
        const int G = i*256 + t;
        const int r = G >> 2;
        const int g = ((G & 3) ^ r ^ (r >> 2)) & 3;
        gload16(Ab + (size_t)(m0 + r) * KDIM + k0 + g*8,
                As + (size_t)(i*256 + wbase) * 8);
      }
    } else if (AMODE == 1){
      const int kk = t >> 3, ch = t & 7;
      const u16* srca = Ab + Abase + (size_t)(k0 + kk) * Mb + m0 + ch*16;
      ushort8v v0 = *(const ushort8v*)srca;
      ushort8v v1 = *(const ushort8v*)(srca + 8);
      const int gsl = kk >> 3, ko7 = kk & 7;
#pragma unroll
      for (int i = 0; i < 8; i++){
        int m = ch*16 + i;
        As[(size_t)((m<<2) | ((gsl ^ m ^ (m>>2)) & 3))*8 + ko7] = (u16)v0[i];
        m += 8;
        As[(size_t)((m<<2) | ((gsl ^ m ^ (m>>2)) & 3))*8 + ko7] = (u16)v1[i];
      }
    } else {
      const int r = t >> 1, kh = (t & 1) << 4;
      const float* sf = Af + (size_t)(m0 + r) * KDIM + k0 + kh;
      float4 f0 = *(const float4*)sf,     f1 = *(const float4*)(sf + 4);
      float4 f2 = *(const float4*)(sf+8), f3 = *(const float4*)(sf + 12);
      ushort8v v0, v1;
      v0[0]=f2bf(f0.x); v0[1]=f2bf(f0.y); v0[2]=f2bf(f0.z); v0[3]=f2bf(f0.w);
      v0[4]=f2bf(f1.x); v0[5]=f2bf(f1.y); v0[6]=f2bf(f1.z); v0[7]=f2bf(f1.w);
      v1[0]=f2bf(f2.x); v1[1]=f2bf(f2.y); v1[2]=f2bf(f2.z); v1[3]=f2bf(f2.w);
      v1[4]=f2bf(f3.x); v1[5]=f2bf(f3.y); v1[6]=f2bf(f3.z); v1[7]=f2bf(f3.w);
      const int key = (r ^ (r >> 2)) & 3;
      *(ushort8v*)&As[(size_t)((r<<2) | ((kh>>3) ^ key))*8]       = v0;
      *(ushort8v*)&As[(size_t)((r<<2) | (((kh>>3)+1) ^ key))*8]   = v1;
    }
    // ---- B staging (always gload_lds) ----
#pragma unroll
    for (int i = 0; i < 2; i++){
      const int G = i*256 + t;
      const int r = G >> 2;
      const int g = ((G & 3) ^ r ^ (r >> 2)) & 3;
      gload16(Wt + (size_t)(n0 + r) * KDIM + k0 + g*8,
              Bs + (size_t)(i*256 + wbase) * 8);
    }
    __syncthreads();

    const int fr = lane & 15, g4 = lane >> 4;
    short8v af[4], bf[4];
#pragma unroll
    for (int mi = 0; mi < 4; mi++){
      const int r = wm + mi*16 + fr;
      af[mi] = *(const short8v*)&As[(size_t)((r<<2) | ((g4 ^ r ^ (r>>2)) & 3)) * 8];
    }
#pragma unroll
    for (int ni = 0; ni < 4; ni++){
      const int r = wn + ni*16 + fr;
      bf[ni] = *(const short8v*)&Bs[(size_t)((r<<2) | ((g4 ^ r ^ (r>>2)) & 3)) * 8];
    }
#pragma unroll
    for (int mi = 0; mi < 4; mi++)
#pragma unroll
      for (int ni = 0; ni < 4; ni++)
        acc[mi][ni] = __builtin_amdgcn_mfma_f32_16x16x32_bf16(af[mi], bf[ni], acc[mi][ni], 0, 0, 0);
  }

  // epilogue: C/D layout col=lane&15, row=(lane>>4)*4+q
  const int fr = lane & 15;
  const int rq = (lane >> 4) * 4;
#pragma unroll
  for (int mi = 0; mi < 4; mi++){
#pragma unroll
    for (int ni = 0; ni < 4; ni++){
      const int gn = n0 + wn + ni*16 + fr;
      const float bs = bias[gn];
#pragma unroll
      for (int q = 0; q < 4; q++){
        const int gm = m0 + wm + mi*16 + rq + q;
        const size_t idx = ((size_t)bb * Mb + gm) * N + gn;
        float v = acc[mi][ni][q] + bs;
        if (RESID) v += bf2f(resid[idx]);
        if (OUTBF) ((u16*)Coutv)[idx] = f2bf(v);
        else       ((float*)Coutv)[idx] = v;
      }
    }
  }
}

// ---------------- in-place log-softmax over rows of 256 ----------------------
__global__ __launch_bounds__(256) void lsm_k(float* __restrict__ o){
  const int row = blockIdx.x * 4 + (threadIdx.x >> 6);
  const int lane = threadIdx.x & 63;
  float* p = o + (size_t)row * NDO + lane * 4;
  float4 v = *(const float4*)p;
  float mx = fmaxf(fmaxf(v.x, v.y), fmaxf(v.z, v.w));
#pragma unroll
  for (int q = 32; q; q >>= 1) mx = fmaxf(mx, __shfl_xor(mx, q));
  float e = __expf(v.x - mx) + __expf(v.y - mx) + __expf(v.z - mx) + __expf(v.w - mx);
#pragma unroll
  for (int q = 32; q; q >>= 1) e += __shfl_xor(e, q);
  const float lse = mx + __logf(e);
  v.x -= lse; v.y -= lse; v.z -= lse; v.w -= lse;
  *(float4*)p = v;
}

// ---------------- launcher ----------------------------------------------------
extern "C" void kernel_launch(void* const* d_in, const int* in_sizes, int n_in,
                              void* d_out, int out_size, void* d_ws, size_t ws_size,
                              hipStream_t stream)
{
  (void)in_sizes; (void)n_in; (void)out_size; (void)ws_size;
  const float* x      = (const float*)d_in[0];
  const float* enc_w  = (const float*)d_in[1];
  const float* enc_b  = (const float*)d_in[2];
  const float* dec_w  = (const float*)d_in[3];
  const float* dec_b  = (const float*)d_in[4];
  const float* ln_s   = (const float*)d_in[5];
  const float* ln_b   = (const float*)d_in[6];
  const float* lam_re = (const float*)d_in[7];
  const float* lam_im = (const float*)d_in[8];
  const float* p_re   = (const float*)d_in[9];
  const float* p_im   = (const float*)d_in[10];
  const float* b_re   = (const float*)d_in[11];
  const float* b_im   = (const float*)d_in[12];
  const float* c_re   = (const float*)d_in[13];
  const float* c_im   = (const float*)d_in[14];
  const float* lstep  = (const float*)d_in[15];
  const float* d_par  = (const float*)d_in[16];
  const float* out_w  = (const float*)d_in[17];
  const float* out_b  = (const float*)d_in[18];

  char* ws = (char*)d_ws;
  u16*    hbuf = (u16*)(ws);
  u16*    zT   = (u16*)  (ws + (size_t)67108864 + 33554432);
  u16*    yT   = (u16*)  (ws + (size_t)67108864 + 2*33554432);
  float2* Kd   = (float2*)(ws + (size_t)67108864 + 3*33554432);
  u16*    Wt   = (u16*)  (ws + (size_t)67108864 + 3*33554432 + 67108864);
  u16*    WtEnc = Wt;                         // 512*512
  u16*    WtOut = Wt + 262144;                // 4 * 512*512
  u16*    WtDec = Wt + 262144*5;              // 256*512
  float*  outp = (float*)d_out;

  // Cauchy weights live in d_out scratch (overwritten by dec gemm at the end)
  float4* cwA = (float4*)d_out;               // 131072 float4
  float4* cwB = cwA + 131072;
  float*  cwS = (float*)(cwB + 131072);

  // 1) weight prep
  prep_k<<<dim3(NLAY*DH*NST/256), 256, 0, stream>>>(lam_re, lam_im, p_re, p_im,
                                                    b_re, b_im, c_re, c_im, cwA, cwB, cwS);
  wconv_k<<<dim3(8, 8, 1), 256, 0, stream>>>(enc_w, WtEnc, KDIM, DH);
  wconv_k<<<dim3(8, 8, NLAY), 256, 0, stream>>>(out_w, WtOut, KDIM, DH);
  wconv_k<<<dim3(8, 4, 1), 256, 0, stream>>>(dec_w, WtDec, KDIM, NDO);
  // 2) DPLR kernels
  cauchy_k<<<dim3(2, DH, NLAY), 256, 0, stream>>>(cwA, cwB, cwS, lstep, Kd);
  kdfft_k<<<dim3(NLAY*DH), 256, 0, stream>>>(Kd);
  // 3) encoder GEMM: h = x @ enc_w + enc_b  (f32 A in, bf16 out)
  gemm_k<2,false,true><<<dim3(DH/128, BL/128, 1), 256, 0, stream>>>(
      x, WtEnc, enc_b, nullptr, hbuf, BL, DH);
  // 4) layers
  for (int i = 0; i < NLAY; i++){
    lnt_k<<<dim3(SL/LTILE, NB), 256, 0, stream>>>(hbuf, ln_s + i*DH, ln_b + i*DH, zT);
    s4conv_k<<<dim3((NB/2)*DH), 256, 0, stream>>>(
        zT, Kd + (size_t)i*DH*4096, d_par + i*DH, yT);
    gemm_k<1,true,true><<<dim3(DH/128, SL/128, NB), 256, 0, stream>>>(
        yT, WtOut + (size_t)i*262144, out_b + i*DH, hbuf, hbuf, SL, DH);
  }
  // 5) decoder (bf16 A in, f32 out) + log_softmax
  gemm_k<0,false,false><<<dim3(NDO/128, BL/128, 1), 256, 0, stream>>>(
      hbuf, WtDec, dec_b, nullptr, outp, BL, NDO);
  lsm_k<<<dim3(BL/4), 256, 0, stream>>>(outp);
}

// Round 9
// 765.866 us; speedup vs baseline: 1.0858x; 1.0858x over previous
//
#include <hip/hip_runtime.h>
#include <hip/hip_bf16.h>

// ---------------- problem constants ----------------
#define NLAY 4
#define DH   512
#define NST  64
#define NB   16
#define SL   2048
#define NDO  256
#define BL   (NB*SL)      // 32768 rows
#define KDIM 512
#define TWOPI 6.283185307179586476925287

typedef unsigned short u16;
typedef __attribute__((ext_vector_type(8))) short  short8v;   // 8 bf16 (4 VGPR) MFMA frag
typedef __attribute__((ext_vector_type(8))) unsigned short ushort8v;
typedef __attribute__((ext_vector_type(4))) float  f32x4;

#define RCPF(x) __builtin_amdgcn_rcpf(x)

// ---------------- small helpers ----------------
__device__ __forceinline__ float bf2f(u16 v){
  union { unsigned u; float f; } x; x.u = ((unsigned)v) << 16; return x.f;
}
__device__ __forceinline__ u16 f2bf(float f){
  union { float f; unsigned u; } x; x.f = f;
  unsigned u = x.u;
  unsigned r = u + 0x7fffu + ((u >> 16) & 1u);   // RNE
  return (u16)(r >> 16);
}
__device__ __forceinline__ void cmulw(float& xr, float& xi, float wr, float wi){
  float tr = xr*wr - xi*wi;
  xi = fmaf(xr, wi, xi*wr);
  xr = tr;
}
__device__ __forceinline__ float gelu_fast(float v){
  const float c0 = 0.7978845608028654f;
  float u = c0 * fmaf(0.044715f, v*v*v, v);
  return v * RCPF(1.0f + __expf(-2.0f * u));
}
// async global(16B/lane) -> LDS (wave-uniform base + lane*16, HW-linear)
__device__ __forceinline__ void gload16(const void* g, void* l){
  __builtin_amdgcn_global_load_lds(
      (__attribute__((address_space(1))) void*)(g),
      (__attribute__((address_space(3))) void*)(l), 16, 0, 0);
}

// ---------------- DFT-16 in registers (radix-4 x radix-4), natural in/out ----
template<int SGN>
__device__ __forceinline__ void dft4w(float& r0, float& i0, float& r1, float& i1,
                                      float& r2, float& i2, float& r3, float& i3){
  const float t0r = r0 + r2, t0i = i0 + i2;
  const float t1r = r0 - r2, t1i = i0 - i2;
  const float t2r = r1 + r3, t2i = i1 + i3;
  const float t3r = r1 - r3, t3i = i1 - i3;
  r0 = t0r + t2r; i0 = t0i + t2i;
  r2 = t0r - t2r; i2 = t0i - t2i;
  if (SGN < 0){ r1 = t1r + t3i; i1 = t1i - t3r; r3 = t1r - t3i; i3 = t1i + t3r; }
  else        { r1 = t1r - t3i; i1 = t1i + t3r; r3 = t1r + t3i; i3 = t1i - t3r; }
}

template<int SGN>
__device__ __forceinline__ void dft16(float* re, float* im){
#pragma unroll
  for (int b = 0; b < 4; b++)
    dft4w<SGN>(re[b], im[b], re[4+b], im[4+b], re[8+b], im[8+b], re[12+b], im[12+b]);
  const float C1 = 0.92387953251128675613f, S1_ = 0.38268343236508977172f;
  const float C2 = 0.70710678118654752440f;
  const float sg = (SGN < 0) ? -1.f : 1.f;
  cmulw(re[5],  im[5],   C1,  sg*S1_);
  cmulw(re[9],  im[9],   C2,  sg*C2);
  cmulw(re[13], im[13],  S1_, sg*C1);
  cmulw(re[6],  im[6],   C2,  sg*C2);
  cmulw(re[10], im[10],  0.f, sg*1.f);
  cmulw(re[14], im[14], -C2,  sg*C2);
  cmulw(re[7],  im[7],   S1_, sg*C1);
  cmulw(re[11], im[11], -C2,  sg*C2);
  cmulw(re[15], im[15], -C1,  sg*(-S1_));
#pragma unroll
  for (int c = 0; c < 4; c++)
    dft4w<SGN>(re[4*c], im[4*c], re[4*c+1], im[4*c+1], re[4*c+2], im[4*c+2], re[4*c+3], im[4*c+3]);
  float tr_, ti_;
#define SWP(A,B) tr_=re[A]; re[A]=re[B]; re[B]=tr_; ti_=im[A]; im[A]=im[B]; im[B]=ti_;
  SWP(1,4) SWP(2,8) SWP(3,12) SWP(6,9) SWP(7,13) SWP(11,14)
#undef SWP
}

// LDS padding: all three stage patterns <=2-way bank conflicts
__device__ __forceinline__ int cxpad(int i){ return i + (i >> 4) + ((i >> 8) << 1); }
#define CXSZ 4384

// forward 4096-pt DIF radix-16 (float2 LDS)
__device__ __forceinline__ void fwd4096(float* re, float* im, float2* cx, int t){
  dft16<-1>(re, im);
  const float a0 = -(float)(TWOPI/4096.0) * (float)t;
#pragma unroll
  for (int k = 0; k < 16; k++){
    if (k){ float sn = __sinf(a0*(float)k), cs = __cosf(a0*(float)k); cmulw(re[k], im[k], cs, sn); }
    cx[cxpad(t + 256*k)] = make_float2(re[k], im[k]);
  }
  __syncthreads();
  const int k1 = t >> 4, m2 = t & 15;
  const int b2 = k1*256 + m2;
#pragma unroll
  for (int j = 0; j < 16; j++){ float2 v = cx[cxpad(b2 + 16*j)]; re[j] = v.x; im[j] = v.y; }
  dft16<-1>(re, im);
  const float b0 = -(float)(TWOPI/256.0) * (float)m2;
  __syncthreads();
#pragma unroll
  for (int k = 0; k < 16; k++){
    if (k){ float sn = __sinf(b0*(float)k), cs = __cosf(b0*(float)k); cmulw(re[k], im[k], cs, sn); }
    cx[cxpad(b2 + 16*k)] = make_float2(re[k], im[k]);
  }
  __syncthreads();
#pragma unroll
  for (int j = 0; j < 16; j++){ float2 v = cx[cxpad(16*t + j)]; re[j] = v.x; im[j] = v.y; }
  dft16<-1>(re, im);
}

// inverse: input = values at positions 16t+k3, output time y[t+256j] (unscaled)
__device__ __forceinline__ void inv4096(float* re, float* im, float2* cx, int t){
  dft16<1>(re, im);
#pragma unroll
  for (int j = 0; j < 16; j++) cx[cxpad(16*t + j)] = make_float2(re[j], im[j]);
  __syncthreads();
  const int k1 = t >> 4, m2 = t & 15;
  const int b2 = k1*256 + m2;
  const float b0 = (float)(TWOPI/256.0) * (float)m2;
#pragma unroll
  for (int k = 0; k < 16; k++){
    float2 v = cx[cxpad(b2 + 16*k)];
    re[k] = v.x; im[k] = v.y;
    if (k){ float sn = __sinf(b0*(float)k), cs = __cosf(b0*(float)k); cmulw(re[k], im[k], cs, sn); }
  }
  dft16<1>(re, im);
  __syncthreads();
#pragma unroll
  for (int j = 0; j < 16; j++) cx[cxpad(b2 + 16*j)] = make_float2(re[j], im[j]);
  __syncthreads();
  const float a0 = (float)(TWOPI/4096.0) * (float)t;
#pragma unroll
  for (int k = 0; k < 16; k++){
    float2 v = cx[cxpad(t + 256*k)];
    re[k] = v.x; im[k] = v.y;
    if (k){ float sn = __sinf(a0*(float)k), cs = __cosf(a0*(float)k); cmulw(re[k], im[k], cs, sn); }
  }
  dft16<1>(re, im);
}

// ---------------- prep: per-(lay,h,n) Woodbury weights ----------------
__global__ __launch_bounds__(256) void prep_k(
  const float* __restrict__ lam_re, const float* __restrict__ lam_im,
  const float* __restrict__ p_re,  const float* __restrict__ p_im,
  const float* __restrict__ b_re,  const float* __restrict__ b_im,
  const float* __restrict__ c_re,  const float* __restrict__ c_im,
  float4* __restrict__ cwA, float4* __restrict__ cwB, float* __restrict__ cwS)
{
  const int i = blockIdx.x * 256 + threadIdx.x;   // < NLAY*DH*NST
  const float lr = lam_re[i], li = lam_im[i];
  const float pr = p_re[i],  pi = p_im[i];
  const float br = b_re[i],  bi = b_im[i];
  const float cr = c_re[i],  ci = c_im[i];
  cwA[i] = make_float4(lr, li, cr*br + ci*bi, cr*bi - ci*br);                  // Lam, conj(C)*B
  cwB[i] = make_float4(cr*pr + ci*pi, cr*pi - ci*pr, pr*br + pi*bi, pr*bi - pi*br); // cC*P, cP*B
  cwS[i] = pr*pr + pi*pi;                                                      // conj(P)*P (real)
}

// ---------------- Cauchy/Woodbury generating function -> at_roots -----------
// g = i*gi with gi = (2/step)*tan(theta/2);  c = 1 + i*tan(theta/2).
// 2 freqs per thread (lb, lb+1024): 16 accumulators fit in arch VGPRs.
__global__ __launch_bounds__(256) void cauchy_k(
    const float4* __restrict__ cwA, const float4* __restrict__ cwB,
    const float* __restrict__ cwS, const float* __restrict__ lstep,
    float2* __restrict__ Kd)
{
  const int t = threadIdx.x;
  const int h = blockIdx.y, lay = blockIdx.z;
  const int lb = blockIdx.x * 256 + t;           // [0, 1024)
  const int wb = (lay*DH + h) * NST;
  const float tw0 = 2.0f * expf(-lstep[lay*DH + h]);   // 2/step

  float T0,T1, g0,g1;
  { float sn, cs;
    sincosf((float)(TWOPI/4096.0)*(float)(lb       ), &sn, &cs); T0 = sn*RCPF(cs); g0 = tw0*T0;
    sincosf((float)(TWOPI/4096.0)*(float)(lb + 1024), &sn, &cs); T1 = sn*RCPF(cs); g1 = tw0*T1;
  }

  float k00r0=0,k00i0=0,k01r0=0,k01i0=0,k10r0=0,k10i0=0,k11r0=0,k11i0=0;
  float k00r1=0,k00i1=0,k01r1=0,k01i1=0,k10r1=0,k10i1=0,k11r1=0,k11i1=0;

#pragma unroll 2
  for (int n = 0; n < NST; n++){
    const float4 A  = cwA[wb + n];
    const float4 Bv = cwB[wb + n];
    const float w11 = cwS[wb + n];
    const float nlr = -A.x;            // -lam_re  (real part of g - Lam)
    const float dr2 = A.x * A.x;
#define CSTEP(J) { \
    const float di = g##J - A.y; \
    const float sI = RCPF(fmaf(di, di, dr2)); \
    const float ivr = nlr * sI, ivi = -di * sI; \
    k00r##J = fmaf(A.z,  ivr, fmaf(-A.w,  ivi, k00r##J)); \
    k00i##J = fmaf(A.z,  ivi, fmaf( A.w,  ivr, k00i##J)); \
    k01r##J = fmaf(Bv.x, ivr, fmaf(-Bv.y, ivi, k01r##J)); \
    k01i##J = fmaf(Bv.x, ivi, fmaf( Bv.y, ivr, k01i##J)); \
    k10r##J = fmaf(Bv.z, ivr, fmaf(-Bv.w, ivi, k10r##J)); \
    k10i##J = fmaf(Bv.z, ivi, fmaf( Bv.w, ivr, k10i##J)); \
    k11r##J = fmaf(w11,  ivr, k11r##J); \
    k11i##J = fmaf(w11,  ivi, k11i##J); }
    CSTEP(0) CSTEP(1)
#undef CSTEP
  }

  float2* kp = Kd + (size_t)(lay*DH + h) * 4096;
#define COUT(J, LOFF) { \
    const float d1r = 1.f + k11r##J, d1i = k11i##J; \
    const float idn = RCPF(fmaf(d1r, d1r, d1i*d1i)); \
    const float wr = k01r##J*k10r##J - k01i##J*k10i##J; \
    const float wi = k01r##J*k10i##J + k01i##J*k10r##J; \
    const float vr = fmaf(wr, d1r,  wi*d1i) * idn; \
    const float vi = fmaf(wi, d1r, -wr*d1i) * idn; \
    const float sr = k00r##J - vr, si = k00i##J - vi; \
    kp[lb + LOFF] = make_float2(fmaf(-T##J, si, sr), fmaf(T##J, sr, si)); }
  COUT(0, 0) COUT(1, 1024)
#undef COUT
}

// ---------------- ifft2048 + fwd fft4096 -> Kd (digit-rev order) -------------
__global__ __launch_bounds__(256) void kdfft_k(float2* __restrict__ Kd){
  __shared__ float  ar[SL], ai[SL];
  __shared__ float2 cx[CXSZ];
  const int t = threadIdx.x;
  const size_t base = (size_t)blockIdx.x * 4096;
#pragma unroll
  for (int q = 0; q < 8; q++){
    const int l = t + 256*q;
    float2 v = Kd[base + l];
    const int brv = __brev((unsigned)l) >> 21;    // 11-bit reverse
    ar[brv] = v.x; ai[brv] = v.y;
  }
  __syncthreads();

  // inverse DFT-2048 (radix-2 DIT, bit-reversed input -> natural K)
  for (int s = 0; s < 11; s++){
    const int half = 1 << s;
    const float fac = (float)(TWOPI) / (float)(2 << s);
#pragma unroll
    for (int q = 0; q < 4; q++){
      const int v = t + 256*q;
      const int pos = v & (half - 1);
      const int i0 = ((v >> s) << (s+1)) + pos;
      const int i1 = i0 + half;
      const float ang = fac * (float)pos;
      const float wc = __cosf(ang), ws = __sinf(ang);   // e^{+i ang}
      const float xr = ar[i1], xi = ai[i1];
      const float tr = wc*xr - ws*xi, ti = fmaf(wc, xi, ws*xr);
      const float ur_ = ar[i0], ui_ = ai[i0];
      ar[i0] = ur_ + tr; ai[i0] = ui_ + ti;
      ar[i1] = ur_ - tr; ai[i1] = ui_ - ti;
    }
    __syncthreads();
  }

  // K (real, scaled 1/2048), zero-pad to 4096, forward DIF -> Kd
  float re[16], im[16];
#pragma unroll
  for (int j = 0; j < 16; j++){
    re[j] = (j < 8) ? ar[t + 256*j] * (1.0f/2048.f) : 0.f;
    im[j] = 0.f;
  }
  fwd4096(re, im, cx, t);
  float2* kp = Kd + base + 16*t;
#pragma unroll
  for (int k = 0; k < 16; k += 2)
    *(float4*)(kp + k) = make_float4(re[k], im[k], re[k+1], im[k+1]);
}

// ---------------- weight convert+transpose f32[K][N] -> bf16[N][K] -----------
__global__ __launch_bounds__(256) void wconv_k(const float* __restrict__ src,
    u16* __restrict__ dst, int K, int N){
  __shared__ u16 tile[64][72];
  const size_t mb = (size_t)blockIdx.z * K * N;
  const int k0 = blockIdx.x * 64, n0 = blockIdx.y * 64;
  const int r = threadIdx.x >> 2, c4 = (threadIdx.x & 3) * 16;
  const float* s = src + mb + (size_t)(k0 + r) * N + n0 + c4;
  float4 f0 = *(const float4*)s, f1 = *(const float4*)(s+4);
  float4 f2 = *(const float4*)(s+8), f3 = *(const float4*)(s+12);
  tile[c4+0][r]=f2bf(f0.x); tile[c4+1][r]=f2bf(f0.y); tile[c4+2][r]=f2bf(f0.z); tile[c4+3][r]=f2bf(f0.w);
  tile[c4+4][r]=f2bf(f1.x); tile[c4+5][r]=f2bf(f1.y); tile[c4+6][r]=f2bf(f1.z); tile[c4+7][r]=f2bf(f1.w);
  tile[c4+8][r]=f2bf(f2.x); tile[c4+9][r]=f2bf(f2.y); tile[c4+10][r]=f2bf(f2.z); tile[c4+11][r]=f2bf(f2.w);
  tile[c4+12][r]=f2bf(f3.x); tile[c4+13][r]=f2bf(f3.y); tile[c4+14][r]=f2bf(f3.z); tile[c4+15][r]=f2bf(f3.w);
  __syncthreads();
  u16* d = dst + mb + (size_t)(n0 + r) * K + k0 + c4;
  *(ushort8v*)d       = *(const ushort8v*)&tile[r][c4];
  *(ushort8v*)(d + 8) = *(const ushort8v*)&tile[r][c4 + 8];
}

// ---------------- fused LayerNorm + transpose: bf16 [b,l,h] -> bf16 [b,h,l] --
#define LTILE 32
__device__ __forceinline__ int lnswz(int h){ return ((h >> 1) + (h >> 6)) & 3; }

__global__ __launch_bounds__(256) void lnt_k(const u16* __restrict__ hsrc,
    const float* __restrict__ gam, const float* __restrict__ bet,
    u16* __restrict__ zT){
  __shared__ u16 tile[DH][LTILE];
  __shared__ float smu[LTILE], srs[LTILE];
  const int t = threadIdx.x;
  const int b = blockIdx.y, l0 = blockIdx.x * LTILE;
  const int r = t >> 3, hb = (t & 7) * 64;
  const u16* p = hsrc + ((size_t)b * SL + l0 + r) * DH + hb;
  float s = 0.f, sq = 0.f;
#pragma unroll
  for (int j8 = 0; j8 < 8; j8++){
    ushort8v w = *(const ushort8v*)(p + j8*8);
    const int h0 = hb + j8*8;
#pragma unroll
    for (int d = 0; d < 8; d++){
      const float f = bf2f((u16)w[d]);
      s += f; sq = fmaf(f, f, sq);
      tile[h0+d][r ^ (lnswz(h0+d) << 3)] = (u16)w[d];
    }
  }
  s  += __shfl_xor(s, 1);  sq += __shfl_xor(sq, 1);
  s  += __shfl_xor(s, 2);  sq += __shfl_xor(sq, 2);
  s  += __shfl_xor(s, 4);  sq += __shfl_xor(sq, 4);
  if ((t & 7) == 0){
    const float mu = s * (1.0f/DH);
    smu[r] = mu;
    srs[r] = rsqrtf(sq * (1.0f/DH) - mu*mu + 1e-6f);
  }
  __syncthreads();

#pragma unroll
  for (int hh = 0; hh < 2; hh++){
    const int h = t + hh*256;
    const float g = gam[h], be = bet[h];
    const int sw = lnswz(h);
    u16* dst = zT + ((size_t)b * DH + h) * SL + l0;
#pragma unroll
    for (int og = 0; og < 4; og++){
      const int lg = og ^ sw;
      ushort8v v = *(const ushort8v*)&tile[h][og*8];
      const float4 m0 = *(const float4*)&smu[lg*8];
      const float4 m1 = *(const float4*)&smu[lg*8 + 4];
      const float4 r0 = *(const float4*)&srs[lg*8];
      const float4 r1 = *(const float4*)&srs[lg*8 + 4];
      ushort8v o;
      o[0] = f2bf(fmaf(bf2f((u16)v[0]) - m0.x, r0.x*g, be));
      o[1] = f2bf(fmaf(bf2f((u16)v[1]) - m0.y, r0.y*g, be));
      o[2] = f2bf(fmaf(bf2f((u16)v[2]) - m0.z, r0.z*g, be));
      o[3] = f2bf(fmaf(bf2f((u16)v[3]) - m0.w, r0.w*g, be));
      o[4] = f2bf(fmaf(bf2f((u16)v[4]) - m1.x, r1.x*g, be));
      o[5] = f2bf(fmaf(bf2f((u16)v[5]) - m1.y, r1.y*g, be));
      o[6] = f2bf(fmaf(bf2f((u16)v[6]) - m1.z, r1.z*g, be));
      o[7] = f2bf(fmaf(bf2f((u16)v[7]) - m1.w, r1.w*g, be));
      *(ushort8v*)(dst + lg*8) = o;
    }
  }
}

// ---------------- S4 FFT convolution + D*u + GELU ----------------------------
__global__ __launch_bounds__(256) void s4conv_k(
    const u16* __restrict__ zT, const float2* __restrict__ Kd,
    const float* __restrict__ dpar, u16* __restrict__ yT)
{
  __shared__ float2 cx[CXSZ];
  const int t = threadIdx.x;
  const int wg = blockIdx.x;          // 8 pairs * 512 channels
  const int h = wg & 511, bp = wg >> 9;
  const u16* r1 = zT + ((size_t)(2*bp) * DH + h) * SL;
  const u16* r2 = r1 + (size_t)DH * SL;
  float ur1[8], ur2[8];
  float re[16], im[16];
#pragma unroll
  for (int j = 0; j < 8; j++){
    ur1[j] = bf2f(r1[t + 256*j]);
    ur2[j] = bf2f(r2[t + 256*j]);
    re[j] = ur1[j]; im[j] = ur2[j];
  }
#pragma unroll
  for (int j = 8; j < 16; j++){ re[j] = 0.f; im[j] = 0.f; }

  fwd4096(re, im, cx, t);

  const float2* kp = Kd + (size_t)h * 4096 + 16*t;
#pragma unroll
  for (int k = 0; k < 16; k += 2){
    float4 w2 = *(const float4*)(kp + k);
    cmulw(re[k],   im[k],   w2.x, w2.y);
    cmulw(re[k+1], im[k+1], w2.z, w2.w);
  }

  inv4096(re, im, cx, t);

  const float Dv = dpar[h];
  u16* y1 = yT + ((size_t)(2*bp) * DH + h) * SL;
  u16* y2 = y1 + (size_t)DH * SL;
#pragma unroll
  for (int j = 0; j < 8; j++){
    float v1 = fmaf(re[j], (1.0f/4096.f), Dv * ur1[j]);
    float v2 = fmaf(im[j], (1.0f/4096.f), Dv * ur2[j]);
    y1[t + 256*j] = f2bf(gelu_fast(v1));
    y2[t + 256*j] = f2bf(gelu_fast(v2));
  }
}

// ---------------- layer GEMM (A = yT bf16 [K][M] batched), R7-proven ---------
// padded [128][40] LDS, manual staging, bf16 out, bf16 residual add.
__global__ __launch_bounds__(256) void gemm_at_k(
    const u16* __restrict__ A, const u16* __restrict__ Wt,
    const float* __restrict__ bias,
    const u16* __restrict__ resid, u16* __restrict__ Cout,
    int Mb, int N)
{
  __shared__ u16 As[128][40];
  __shared__ u16 Bs[128][40];
  const int t = threadIdx.x;
  const int n0 = blockIdx.x * 128, m0 = blockIdx.y * 128, bb = blockIdx.z;
  const int lane = t & 63, wv = t >> 6;
  const int wm = (wv >> 1) * 64, wn = (wv & 1) * 64;
  f32x4 acc[4][4];
#pragma unroll
  for (int mi = 0; mi < 4; mi++)
#pragma unroll
    for (int ni = 0; ni < 4; ni++) acc[mi][ni] = {0.f, 0.f, 0.f, 0.f};

  const size_t Abase = (size_t)bb * KDIM * Mb;

  for (int k0 = 0; k0 < KDIM; k0 += 32){
    __syncthreads();
    {
      const int kk = t >> 3, ch = t & 7;
      const u16* srca = A + Abase + (size_t)(k0 + kk) * Mb + m0 + ch*16;
      ushort8v v0 = *(const ushort8v*)srca;
      ushort8v v1 = *(const ushort8v*)(srca + 8);
      const int col = (kk & 7) | (((kk >> 3) ^ (ch & 3)) << 3);
#pragma unroll
      for (int i = 0; i < 8; i++){
        As[ch*16 + i][col]     = (u16)v0[i];
        As[ch*16 + 8 + i][col] = (u16)v1[i];
      }
    }
    {
      const int r = t >> 1, kh = (t & 1) << 4;
      const u16* srcb = Wt + (size_t)(n0 + r) * KDIM + k0 + kh;
      ushort8v v0 = *(const ushort8v*)srcb;
      ushort8v v1 = *(const ushort8v*)(srcb + 8);
      const int s3 = (r >> 4) & 3;
      const int c0 = (((kh >> 3) ^ s3) << 3);
      const int c1 = ((((kh >> 3) + 1) ^ s3) << 3);
      *(ushort8v*)&Bs[r][c0] = v0;
      *(ushort8v*)&Bs[r][c1] = v1;
    }
    __syncthreads();

    const int ko = (lane >> 4) * 8;
    const int fr = lane & 15;
    short8v af[4], bf[4];
#pragma unroll
    for (int mi = 0; mi < 4; mi++){
      const int col = (((ko >> 3) ^ (((wm >> 4) + mi) & 3)) << 3);
      af[mi] = *(const short8v*)&As[wm + mi*16 + fr][col];
    }
#pragma unroll
    for (int ni = 0; ni < 4; ni++){
      const int col = (((ko >> 3) ^ (((wn >> 4) + ni) & 3)) << 3);
      bf[ni] = *(const short8v*)&Bs[wn + ni*16 + fr][col];
    }
#pragma unroll
    for (int mi = 0; mi < 4; mi++)
#pragma unroll
      for (int ni = 0; ni < 4; ni++)
        acc[mi][ni] = __builtin_amdgcn_mfma_f32_16x16x32_bf16(af[mi], bf[ni], acc[mi][ni], 0, 0, 0);
  }

  const int fr = lane & 15;
  const int rq = (lane >> 4) * 4;
#pragma unroll
  for (int mi = 0; mi < 4; mi++){
#pragma unroll
    for (int ni = 0; ni < 4; ni++){
      const int gn = n0 + wn + ni*16 + fr;
      const float bs = bias[gn];
#pragma unroll
      for (int q = 0; q < 4; q++){
        const int gm = m0 + wm + mi*16 + rq + q;
        const size_t idx = ((size_t)bb * Mb + gm) * N + gn;
        Cout[idx] = f2bf(acc[mi][ni][q] + bs + bf2f(resid[idx]));
      }
    }
  }
}

// ---------------- enc/dec GEMM: granule layout + global_load_lds -------------
// G(r,g) = (r<<2) | ((g ^ r ^ (r>>2)) & 3), 16B granules (8 bf16 of a row).
// AMODE: 0 = bf16 [M][K] (gload); 2 = f32 [M][K] (reg convert). No residual.
template<int AMODE, bool OUTBF>
__global__ __launch_bounds__(256) void gemm_k(
    const void* __restrict__ Aptr, const u16* __restrict__ Wt,
    const float* __restrict__ bias, void* __restrict__ Coutv,
    int Mb, int N)
{
  __shared__ u16 As[4096];   // 512 granules
  __shared__ u16 Bs[4096];
  const int t = threadIdx.x;
  const int n0 = blockIdx.x * 128, m0 = blockIdx.y * 128;
  const int lane = t & 63, wv = t >> 6;
  const int wm = (wv >> 1) * 64, wn = (wv & 1) * 64;
  const int wbase = t & 192;           // wave granule base
  f32x4 acc[4][4];
#pragma unroll
  for (int mi = 0; mi < 4; mi++)
#pragma unroll
    for (int ni = 0; ni < 4; ni++) acc[mi][ni] = {0.f, 0.f, 0.f, 0.f};

  const u16*  Ab = (const u16*)Aptr;
  const float* Af = (const float*)Aptr;

  for (int k0 = 0; k0 < KDIM; k0 += 32){
    __syncthreads();
    if (AMODE == 0){
#pragma unroll
      for (int i = 0; i < 2; i++){
        const int G = i*256 + t;
        const int r = G >> 2;
        const int g = ((G & 3) ^ r ^ (r >> 2)) & 3;
        gload16(Ab + (size_t)(m0 + r) * KDIM + k0 + g*8,
                As + (size_t)(i*256 + wbase) * 8);
      }
    } else {
      const int r = t >> 1, kh = (t & 1) << 4;
      const float* sf = Af + (size_t)(m0 + r) * KDIM + k0 + kh;
      float4 f0 = *(const float4*)sf,     f1 = *(const float4*)(sf + 4);
      float4 f2 = *(const float4*)(sf+8), f3 = *(const float4*)(sf + 12);
      ushort8v v0, v1;
      v0[0]=f2bf(f0.x); v0[1]=f2bf(f0.y); v0[2]=f2bf(f0.z); v0[3]=f2bf(f0.w);
      v0[4]=f2bf(f1.x); v0[5]=f2bf(f1.y); v0[6]=f2bf(f1.z); v0[7]=f2bf(f1.w);
      v1[0]=f2bf(f2.x); v1[1]=f2bf(f2.y); v1[2]=f2bf(f2.z); v1[3]=f2bf(f2.w);
      v1[4]=f2bf(f3.x); v1[5]=f2bf(f3.y); v1[6]=f2bf(f3.z); v1[7]=f2bf(f3.w);
      const int key = (r ^ (r >> 2)) & 3;
      *(ushort8v*)&As[(size_t)((r<<2) | ((kh>>3) ^ key))*8]       = v0;
      *(ushort8v*)&As[(size_t)((r<<2) | (((kh>>3)+1) ^ key))*8]   = v1;
    }
#pragma unroll
    for (int i = 0; i < 2; i++){
      const int G = i*256 + t;
      const int r = G >> 2;
      const int g = ((G & 3) ^ r ^ (r >> 2)) & 3;
      gload16(Wt + (size_t)(n0 + r) * KDIM + k0 + g*8,
              Bs + (size_t)(i*256 + wbase) * 8);
    }
    __syncthreads();

    const int fr = lane & 15, g4 = lane >> 4;
    short8v af[4], bf[4];
#pragma unroll
    for (int mi = 0; mi < 4; mi++){
      const int r = wm + mi*16 + fr;
      af[mi] = *(const short8v*)&As[(size_t)((r<<2) | ((g4 ^ r ^ (r>>2)) & 3)) * 8];
    }
#pragma unroll
    for (int ni = 0; ni < 4; ni++){
      const int r = wn + ni*16 + fr;
      bf[ni] = *(const short8v*)&Bs[(size_t)((r<<2) | ((g4 ^ r ^ (r>>2)) & 3)) * 8];
    }
#pragma unroll
    for (int mi = 0; mi < 4; mi++)
#pragma unroll
      for (int ni = 0; ni < 4; ni++)
        acc[mi][ni] = __builtin_amdgcn_mfma_f32_16x16x32_bf16(af[mi], bf[ni], acc[mi][ni], 0, 0, 0);
  }

  const int fr = lane & 15;
  const int rq = (lane >> 4) * 4;
#pragma unroll
  for (int mi = 0; mi < 4; mi++){
#pragma unroll
    for (int ni = 0; ni < 4; ni++){
      const int gn = n0 + wn + ni*16 + fr;
      const float bs = bias[gn];
#pragma unroll
      for (int q = 0; q < 4; q++){
        const int gm = m0 + wm + mi*16 + rq + q;
        const size_t idx = (size_t)gm * N + gn;
        float v = acc[mi][ni][q] + bs;
        if (OUTBF) ((u16*)Coutv)[idx] = f2bf(v);
        else       ((float*)Coutv)[idx] = v;
      }
    }
  }
}

// ---------------- in-place log-softmax over rows of 256 ----------------------
__global__ __launch_bounds__(256) void lsm_k(float* __restrict__ o){
  const int row = blockIdx.x * 4 + (threadIdx.x >> 6);
  const int lane = threadIdx.x & 63;
  float* p = o + (size_t)row * NDO + lane * 4;
  float4 v = *(const float4*)p;
  float mx = fmaxf(fmaxf(v.x, v.y), fmaxf(v.z, v.w));
#pragma unroll
  for (int q = 32; q; q >>= 1) mx = fmaxf(mx, __shfl_xor(mx, q));
  float e = __expf(v.x - mx) + __expf(v.y - mx) + __expf(v.z - mx) + __expf(v.w - mx);
#pragma unroll
  for (int q = 32; q; q >>= 1) e += __shfl_xor(e, q);
  const float lse = mx + __logf(e);
  v.x -= lse; v.y -= lse; v.z -= lse; v.w -= lse;
  *(float4*)p = v;
}

// ---------------- launcher ----------------------------------------------------
extern "C" void kernel_launch(void* const* d_in, const int* in_sizes, int n_in,
                              void* d_out, int out_size, void* d_ws, size_t ws_size,
                              hipStream_t stream)
{
  (void)in_sizes; (void)n_in; (void)out_size; (void)ws_size;
  const float* x      = (const float*)d_in[0];
  const float* enc_w  = (const float*)d_in[1];
  const float* enc_b  = (const float*)d_in[2];
  const float* dec_w  = (const float*)d_in[3];
  const float* dec_b  = (const float*)d_in[4];
  const float* ln_s   = (const float*)d_in[5];
  const float* ln_b   = (const float*)d_in[6];
  const float* lam_re = (const float*)d_in[7];
  const float* lam_im = (const float*)d_in[8];
  const float* p_re   = (const float*)d_in[9];
  const float* p_im   = (const float*)d_in[10];
  const float* b_re   = (const float*)d_in[11];
  const float* b_im   = (const float*)d_in[12];
  const float* c_re   = (const float*)d_in[13];
  const float* c_im   = (const float*)d_in[14];
  const float* lstep  = (const float*)d_in[15];
  const float* d_par  = (const float*)d_in[16];
  const float* out_w  = (const float*)d_in[17];
  const float* out_b  = (const float*)d_in[18];

  char* ws = (char*)d_ws;
  u16*    hbuf = (u16*)(ws);
  u16*    zT   = (u16*)  (ws + (size_t)67108864 + 33554432);
  u16*    yT   = (u16*)  (ws + (size_t)67108864 + 2*33554432);
  float2* Kd   = (float2*)(ws + (size_t)67108864 + 3*33554432);
  u16*    Wt   = (u16*)  (ws + (size_t)67108864 + 3*33554432 + 67108864);
  u16*    WtEnc = Wt;                         // 512*512
  u16*    WtOut = Wt + 262144;                // 4 * 512*512
  u16*    WtDec = Wt + 262144*5;              // 256*512
  float*  outp = (float*)d_out;

  // Cauchy weights live in d_out scratch (overwritten by dec gemm at the end)
  float4* cwA = (float4*)d_out;               // 131072 float4
  float4* cwB = cwA + 131072;
  float*  cwS = (float*)(cwB + 131072);

  // 1) weight prep
  prep_k<<<dim3(NLAY*DH*NST/256), 256, 0, stream>>>(lam_re, lam_im, p_re, p_im,
                                                    b_re, b_im, c_re, c_im, cwA, cwB, cwS);
  wconv_k<<<dim3(8, 8, 1), 256, 0, stream>>>(enc_w, WtEnc, KDIM, DH);
  wconv_k<<<dim3(8, 8, NLAY), 256, 0, stream>>>(out_w, WtOut, KDIM, DH);
  wconv_k<<<dim3(8, 4, 1), 256, 0, stream>>>(dec_w, WtDec, KDIM, NDO);
  // 2) DPLR kernels
  cauchy_k<<<dim3(4, DH, NLAY), 256, 0, stream>>>(cwA, cwB, cwS, lstep, Kd);
  kdfft_k<<<dim3(NLAY*DH), 256, 0, stream>>>(Kd);
  // 3) encoder GEMM: h = x @ enc_w + enc_b  (f32 A in, bf16 out)
  gemm_k<2,true><<<dim3(DH/128, BL/128, 1), 256, 0, stream>>>(
      x, WtEnc, enc_b, hbuf, BL, DH);
  // 4) layers
  for (int i = 0; i < NLAY; i++){
    lnt_k<<<dim3(SL/LTILE, NB), 256, 0, stream>>>(hbuf, ln_s + i*DH, ln_b + i*DH, zT);
    s4conv_k<<<dim3((NB/2)*DH), 256, 0, stream>>>(
        zT, Kd + (size_t)i*DH*4096, d_par + i*DH, yT);
    gemm_at_k<<<dim3(DH/128, SL/128, NB), 256, 0, stream>>>(
        yT, WtOut + (size_t)i*262144, out_b + i*DH, hbuf, hbuf, SL, DH);
  }
  // 5) decoder (bf16 A in, f32 out) + log_softmax
  gemm_k<0,false><<<dim3(NDO/128, BL/128, 1), 256, 0, stream>>>(
      hbuf, WtDec, dec_b, outp, BL, NDO);
  lsm_k<<<dim3(BL/4), 256, 0, stream>>>(outp);
}

// Round 10
// 732.008 us; speedup vs baseline: 1.1360x; 1.0463x over previous
//
#include <hip/hip_runtime.h>
#include <hip/hip_bf16.h>

// ---------------- problem constants ----------------
#define NLAY 4
#define DH   512
#define NST  64
#define NB   16
#define SL   2048
#define NDO  256
#define BL   (NB*SL)      // 32768 rows
#define KDIM 512
#define TWOPI 6.283185307179586476925287

typedef unsigned short u16;
typedef __attribute__((ext_vector_type(8))) short  short8v;   // 8 bf16 (4 VGPR) MFMA frag
typedef __attribute__((ext_vector_type(8))) unsigned short ushort8v;
typedef __attribute__((ext_vector_type(4))) float  f32x4;
typedef __attribute__((ext_vector_type(2))) unsigned int uint2v;

#define RCPF(x) __builtin_amdgcn_rcpf(x)

// ---------------- small helpers ----------------
__device__ __forceinline__ float bf2f(u16 v){
  union { unsigned u; float f; } x; x.u = ((unsigned)v) << 16; return x.f;
}
__device__ __forceinline__ u16 f2bf(float f){
  union { float f; unsigned u; } x; x.f = f;
  unsigned u = x.u;
  unsigned r = u + 0x7fffu + ((u >> 16) & 1u);   // RNE
  return (u16)(r >> 16);
}
__device__ __forceinline__ void cmulw(float& xr, float& xi, float wr, float wi){
  float tr = xr*wr - xi*wi;
  xi = fmaf(xr, wi, xi*wr);
  xr = tr;
}
__device__ __forceinline__ float gelu_fast(float v){
  const float c0 = 0.7978845608028654f;
  float u = c0 * fmaf(0.044715f, v*v*v, v);
  return v * RCPF(1.0f + __expf(-2.0f * u));
}
// async global(16B/lane) -> LDS (wave-uniform base + lane*16, HW-linear)
__device__ __forceinline__ void gload16(const void* g, void* l){
  __builtin_amdgcn_global_load_lds(
      (__attribute__((address_space(1))) void*)(g),
      (__attribute__((address_space(3))) void*)(l), 16, 0, 0);
}

// ---------------- DFT-16 in registers (radix-4 x radix-4), natural in/out ----
template<int SGN>
__device__ __forceinline__ void dft4w(float& r0, float& i0, float& r1, float& i1,
                                      float& r2, float& i2, float& r3, float& i3){
  const float t0r = r0 + r2, t0i = i0 + i2;
  const float t1r = r0 - r2, t1i = i0 - i2;
  const float t2r = r1 + r3, t2i = i1 + i3;
  const float t3r = r1 - r3, t3i = i1 - i3;
  r0 = t0r + t2r; i0 = t0i + t2i;
  r2 = t0r - t2r; i2 = t0i - t2i;
  if (SGN < 0){ r1 = t1r + t3i; i1 = t1i - t3r; r3 = t1r - t3i; i3 = t1i + t3r; }
  else        { r1 = t1r - t3i; i1 = t1i + t3r; r3 = t1r + t3i; i3 = t1i - t3r; }
}

template<int SGN>
__device__ __forceinline__ void dft16(float* re, float* im){
#pragma unroll
  for (int b = 0; b < 4; b++)
    dft4w<SGN>(re[b], im[b], re[4+b], im[4+b], re[8+b], im[8+b], re[12+b], im[12+b]);
  const float C1 = 0.92387953251128675613f, S1_ = 0.38268343236508977172f;
  const float C2 = 0.70710678118654752440f;
  const float sg = (SGN < 0) ? -1.f : 1.f;
  cmulw(re[5],  im[5],   C1,  sg*S1_);
  cmulw(re[9],  im[9],   C2,  sg*C2);
  cmulw(re[13], im[13],  S1_, sg*C1);
  cmulw(re[6],  im[6],   C2,  sg*C2);
  cmulw(re[10], im[10],  0.f, sg*1.f);
  cmulw(re[14], im[14], -C2,  sg*C2);
  cmulw(re[7],  im[7],   S1_, sg*C1);
  cmulw(re[11], im[11], -C2,  sg*C2);
  cmulw(re[15], im[15], -C1,  sg*(-S1_));
#pragma unroll
  for (int c = 0; c < 4; c++)
    dft4w<SGN>(re[4*c], im[4*c], re[4*c+1], im[4*c+1], re[4*c+2], im[4*c+2], re[4*c+3], im[4*c+3]);
  float tr_, ti_;
#define SWP(A,B) tr_=re[A]; re[A]=re[B]; re[B]=tr_; ti_=im[A]; im[A]=im[B]; im[B]=ti_;
  SWP(1,4) SWP(2,8) SWP(3,12) SWP(6,9) SWP(7,13) SWP(11,14)
#undef SWP
}

// LDS padding: all three stage patterns <=2-way bank conflicts
__device__ __forceinline__ int cxpad(int i){ return i + (i >> 4) + ((i >> 8) << 1); }
#define CXSZ 4384

// forward 4096-pt DIF radix-16 (float2 LDS)
__device__ __forceinline__ void fwd4096(float* re, float* im, float2* cx, int t){
  dft16<-1>(re, im);
  const float a0 = -(float)(TWOPI/4096.0) * (float)t;
#pragma unroll
  for (int k = 0; k < 16; k++){
    if (k){ float sn = __sinf(a0*(float)k), cs = __cosf(a0*(float)k); cmulw(re[k], im[k], cs, sn); }
    cx[cxpad(t + 256*k)] = make_float2(re[k], im[k]);
  }
  __syncthreads();
  const int k1 = t >> 4, m2 = t & 15;
  const int b2 = k1*256 + m2;
#pragma unroll
  for (int j = 0; j < 16; j++){ float2 v = cx[cxpad(b2 + 16*j)]; re[j] = v.x; im[j] = v.y; }
  dft16<-1>(re, im);
  const float b0 = -(float)(TWOPI/256.0) * (float)m2;
  __syncthreads();
#pragma unroll
  for (int k = 0; k < 16; k++){
    if (k){ float sn = __sinf(b0*(float)k), cs = __cosf(b0*(float)k); cmulw(re[k], im[k], cs, sn); }
    cx[cxpad(b2 + 16*k)] = make_float2(re[k], im[k]);
  }
  __syncthreads();
#pragma unroll
  for (int j = 0; j < 16; j++){ float2 v = cx[cxpad(16*t + j)]; re[j] = v.x; im[j] = v.y; }
  dft16<-1>(re, im);
}

// inverse: input = values at positions 16t+k3, output time y[t+256j] (unscaled)
__device__ __forceinline__ void inv4096(float* re, float* im, float2* cx, int t){
  dft16<1>(re, im);
#pragma unroll
  for (int j = 0; j < 16; j++) cx[cxpad(16*t + j)] = make_float2(re[j], im[j]);
  __syncthreads();
  const int k1 = t >> 4, m2 = t & 15;
  const int b2 = k1*256 + m2;
  const float b0 = (float)(TWOPI/256.0) * (float)m2;
#pragma unroll
  for (int k = 0; k < 16; k++){
    float2 v = cx[cxpad(b2 + 16*k)];
    re[k] = v.x; im[k] = v.y;
    if (k){ float sn = __sinf(b0*(float)k), cs = __cosf(b0*(float)k); cmulw(re[k], im[k], cs, sn); }
  }
  dft16<1>(re, im);
  __syncthreads();
#pragma unroll
  for (int j = 0; j < 16; j++) cx[cxpad(b2 + 16*j)] = make_float2(re[j], im[j]);
  __syncthreads();
  const float a0 = (float)(TWOPI/4096.0) * (float)t;
#pragma unroll
  for (int k = 0; k < 16; k++){
    float2 v = cx[cxpad(t + 256*k)];
    re[k] = v.x; im[k] = v.y;
    if (k){ float sn = __sinf(a0*(float)k), cs = __cosf(a0*(float)k); cmulw(re[k], im[k], cs, sn); }
  }
  dft16<1>(re, im);
}

// ---------------- prep: per-(lay,h,n) Woodbury weights ----------------
__global__ __launch_bounds__(256) void prep_k(
  const float* __restrict__ lam_re, const float* __restrict__ lam_im,
  const float* __restrict__ p_re,  const float* __restrict__ p_im,
  const float* __restrict__ b_re,  const float* __restrict__ b_im,
  const float* __restrict__ c_re,  const float* __restrict__ c_im,
  float4* __restrict__ cwA, float4* __restrict__ cwB, float* __restrict__ cwS)
{
  const int i = blockIdx.x * 256 + threadIdx.x;   // < NLAY*DH*NST
  const float lr = lam_re[i], li = lam_im[i];
  const float pr = p_re[i],  pi = p_im[i];
  const float br = b_re[i],  bi = b_im[i];
  const float cr = c_re[i],  ci = c_im[i];
  cwA[i] = make_float4(lr, li, cr*br + ci*bi, cr*bi - ci*br);                  // Lam, conj(C)*B
  cwB[i] = make_float4(cr*pr + ci*pi, cr*pi - ci*pr, pr*br + pi*bi, pr*bi - pi*br); // cC*P, cP*B
  cwS[i] = pr*pr + pi*pi;                                                      // conj(P)*P (real)
}

// ---------------- Cauchy/Woodbury generating function -> at_roots -----------
// g = i*gi with gi = (2/step)*tan(theta/2);  c = 1 + i*tan(theta/2).
// 2 freqs per thread (lb, lb+1024). Near its VALU floor (~122 us) — frozen.
__global__ __launch_bounds__(256) void cauchy_k(
    const float4* __restrict__ cwA, const float4* __restrict__ cwB,
    const float* __restrict__ cwS, const float* __restrict__ lstep,
    float2* __restrict__ Kd)
{
  const int t = threadIdx.x;
  const int h = blockIdx.y, lay = blockIdx.z;
  const int lb = blockIdx.x * 256 + t;           // [0, 1024)
  const int wb = (lay*DH + h) * NST;
  const float tw0 = 2.0f * expf(-lstep[lay*DH + h]);   // 2/step

  float T0,T1, g0,g1;
  { float sn, cs;
    sincosf((float)(TWOPI/4096.0)*(float)(lb       ), &sn, &cs); T0 = sn*RCPF(cs); g0 = tw0*T0;
    sincosf((float)(TWOPI/4096.0)*(float)(lb + 1024), &sn, &cs); T1 = sn*RCPF(cs); g1 = tw0*T1;
  }

  float k00r0=0,k00i0=0,k01r0=0,k01i0=0,k10r0=0,k10i0=0,k11r0=0,k11i0=0;
  float k00r1=0,k00i1=0,k01r1=0,k01i1=0,k10r1=0,k10i1=0,k11r1=0,k11i1=0;

#pragma unroll 2
  for (int n = 0; n < NST; n++){
    const float4 A  = cwA[wb + n];
    const float4 Bv = cwB[wb + n];
    const float w11 = cwS[wb + n];
    const float nlr = -A.x;            // -lam_re  (real part of g - Lam)
    const float dr2 = A.x * A.x;
#define CSTEP(J) { \
    const float di = g##J - A.y; \
    const float sI = RCPF(fmaf(di, di, dr2)); \
    const float ivr = nlr * sI, ivi = -di * sI; \
    k00r##J = fmaf(A.z,  ivr, fmaf(-A.w,  ivi, k00r##J)); \
    k00i##J = fmaf(A.z,  ivi, fmaf( A.w,  ivr, k00i##J)); \
    k01r##J = fmaf(Bv.x, ivr, fmaf(-Bv.y, ivi, k01r##J)); \
    k01i##J = fmaf(Bv.x, ivi, fmaf( Bv.y, ivr, k01i##J)); \
    k10r##J = fmaf(Bv.z, ivr, fmaf(-Bv.w, ivi, k10r##J)); \
    k10i##J = fmaf(Bv.z, ivi, fmaf( Bv.w, ivr, k10i##J)); \
    k11r##J = fmaf(w11,  ivr, k11r##J); \
    k11i##J = fmaf(w11,  ivi, k11i##J); }
    CSTEP(0) CSTEP(1)
#undef CSTEP
  }

  float2* kp = Kd + (size_t)(lay*DH + h) * 4096;
#define COUT(J, LOFF) { \
    const float d1r = 1.f + k11r##J, d1i = k11i##J; \
    const float idn = RCPF(fmaf(d1r, d1r, d1i*d1i)); \
    const float wr = k01r##J*k10r##J - k01i##J*k10i##J; \
    const float wi = k01r##J*k10i##J + k01i##J*k10r##J; \
    const float vr = fmaf(wr, d1r,  wi*d1i) * idn; \
    const float vi = fmaf(wi, d1r, -wr*d1i) * idn; \
    const float sr = k00r##J - vr, si = k00i##J - vi; \
    kp[lb + LOFF] = make_float2(fmaf(-T##J, si, sr), fmaf(T##J, sr, si)); }
  COUT(0, 0) COUT(1, 1024)
#undef COUT
}

// ---------------- ifft2048 + fwd fft4096 -> Kd (digit-rev order) -------------
__global__ __launch_bounds__(256) void kdfft_k(float2* __restrict__ Kd){
  __shared__ float  ar[SL], ai[SL];
  __shared__ float2 cx[CXSZ];
  const int t = threadIdx.x;
  const size_t base = (size_t)blockIdx.x * 4096;
#pragma unroll
  for (int q = 0; q < 8; q++){
    const int l = t + 256*q;
    float2 v = Kd[base + l];
    const int brv = __brev((unsigned)l) >> 21;    // 11-bit reverse
    ar[brv] = v.x; ai[brv] = v.y;
  }
  __syncthreads();

  // inverse DFT-2048 (radix-2 DIT, bit-reversed input -> natural K)
  for (int s = 0; s < 11; s++){
    const int half = 1 << s;
    const float fac = (float)(TWOPI) / (float)(2 << s);
#pragma unroll
    for (int q = 0; q < 4; q++){
      const int v = t + 256*q;
      const int pos = v & (half - 1);
      const int i0 = ((v >> s) << (s+1)) + pos;
      const int i1 = i0 + half;
      const float ang = fac * (float)pos;
      const float wc = __cosf(ang), ws = __sinf(ang);   // e^{+i ang}
      const float xr = ar[i1], xi = ai[i1];
      const float tr = wc*xr - ws*xi, ti = fmaf(wc, xi, ws*xr);
      const float ur_ = ar[i0], ui_ = ai[i0];
      ar[i0] = ur_ + tr; ai[i0] = ui_ + ti;
      ar[i1] = ur_ - tr; ai[i1] = ui_ - ti;
    }
    __syncthreads();
  }

  // K (real, scaled 1/2048), zero-pad to 4096, forward DIF -> Kd
  float re[16], im[16];
#pragma unroll
  for (int j = 0; j < 16; j++){
    re[j] = (j < 8) ? ar[t + 256*j] * (1.0f/2048.f) : 0.f;
    im[j] = 0.f;
  }
  fwd4096(re, im, cx, t);
  float2* kp = Kd + base + 16*t;
#pragma unroll
  for (int k = 0; k < 16; k += 2)
    *(float4*)(kp + k) = make_float4(re[k], im[k], re[k+1], im[k+1]);
}

// ---------------- weight convert+transpose f32[K][N] -> bf16[N][K] -----------
__global__ __launch_bounds__(256) void wconv_k(const float* __restrict__ src,
    u16* __restrict__ dst, int K, int N){
  __shared__ u16 tile[64][72];
  const size_t mb = (size_t)blockIdx.z * K * N;
  const int k0 = blockIdx.x * 64, n0 = blockIdx.y * 64;
  const int r = threadIdx.x >> 2, c4 = (threadIdx.x & 3) * 16;
  const float* s = src + mb + (size_t)(k0 + r) * N + n0 + c4;
  float4 f0 = *(const float4*)s, f1 = *(const float4*)(s+4);
  float4 f2 = *(const float4*)(s+8), f3 = *(const float4*)(s+12);
  tile[c4+0][r]=f2bf(f0.x); tile[c4+1][r]=f2bf(f0.y); tile[c4+2][r]=f2bf(f0.z); tile[c4+3][r]=f2bf(f0.w);
  tile[c4+4][r]=f2bf(f1.x); tile[c4+5][r]=f2bf(f1.y); tile[c4+6][r]=f2bf(f1.z); tile[c4+7][r]=f2bf(f1.w);
  tile[c4+8][r]=f2bf(f2.x); tile[c4+9][r]=f2bf(f2.y); tile[c4+10][r]=f2bf(f2.z); tile[c4+11][r]=f2bf(f2.w);
  tile[c4+12][r]=f2bf(f3.x); tile[c4+13][r]=f2bf(f3.y); tile[c4+14][r]=f2bf(f3.z); tile[c4+15][r]=f2bf(f3.w);
  __syncthreads();
  u16* d = dst + mb + (size_t)(n0 + r) * K + k0 + c4;
  *(ushort8v*)d       = *(const ushort8v*)&tile[r][c4];
  *(ushort8v*)(d + 8) = *(const ushort8v*)&tile[r][c4 + 8];
}

// ---------------- fused LayerNorm + transpose: bf16 [b,l,h] -> bf16 [b,h,l] --
#define LTILE 32
__device__ __forceinline__ int lnswz(int h){ return ((h >> 1) + (h >> 6)) & 3; }

__global__ __launch_bounds__(256) void lnt_k(const u16* __restrict__ hsrc,
    const float* __restrict__ gam, const float* __restrict__ bet,
    u16* __restrict__ zT){
  __shared__ u16 tile[DH][LTILE];
  __shared__ float smu[LTILE], srs[LTILE];
  const int t = threadIdx.x;
  const int b = blockIdx.y, l0 = blockIdx.x * LTILE;
  const int r = t >> 3, hb = (t & 7) * 64;
  const u16* p = hsrc + ((size_t)b * SL + l0 + r) * DH + hb;
  float s = 0.f, sq = 0.f;
#pragma unroll
  for (int j8 = 0; j8 < 8; j8++){
    ushort8v w = *(const ushort8v*)(p + j8*8);
    const int h0 = hb + j8*8;
#pragma unroll
    for (int d = 0; d < 8; d++){
      const float f = bf2f((u16)w[d]);
      s += f; sq = fmaf(f, f, sq);
      tile[h0+d][r ^ (lnswz(h0+d) << 3)] = (u16)w[d];
    }
  }
  s  += __shfl_xor(s, 1);  sq += __shfl_xor(sq, 1);
  s  += __shfl_xor(s, 2);  sq += __shfl_xor(sq, 2);
  s  += __shfl_xor(s, 4);  sq += __shfl_xor(sq, 4);
  if ((t & 7) == 0){
    const float mu = s * (1.0f/DH);
    smu[r] = mu;
    srs[r] = rsqrtf(sq * (1.0f/DH) - mu*mu + 1e-6f);
  }
  __syncthreads();

#pragma unroll
  for (int hh = 0; hh < 2; hh++){
    const int h = t + hh*256;
    const float g = gam[h], be = bet[h];
    const int sw = lnswz(h);
    u16* dst = zT + ((size_t)b * DH + h) * SL + l0;
#pragma unroll
    for (int og = 0; og < 4; og++){
      const int lg = og ^ sw;
      ushort8v v = *(const ushort8v*)&tile[h][og*8];
      const float4 m0 = *(const float4*)&smu[lg*8];
      const float4 m1 = *(const float4*)&smu[lg*8 + 4];
      const float4 r0 = *(const float4*)&srs[lg*8];
      const float4 r1 = *(const float4*)&srs[lg*8 + 4];
      ushort8v o;
      o[0] = f2bf(fmaf(bf2f((u16)v[0]) - m0.x, r0.x*g, be));
      o[1] = f2bf(fmaf(bf2f((u16)v[1]) - m0.y, r0.y*g, be));
      o[2] = f2bf(fmaf(bf2f((u16)v[2]) - m0.z, r0.z*g, be));
      o[3] = f2bf(fmaf(bf2f((u16)v[3]) - m0.w, r0.w*g, be));
      o[4] = f2bf(fmaf(bf2f((u16)v[4]) - m1.x, r1.x*g, be));
      o[5] = f2bf(fmaf(bf2f((u16)v[5]) - m1.y, r1.y*g, be));
      o[6] = f2bf(fmaf(bf2f((u16)v[6]) - m1.z, r1.z*g, be));
      o[7] = f2bf(fmaf(bf2f((u16)v[7]) - m1.w, r1.w*g, be));
      *(ushort8v*)(dst + lg*8) = o;
    }
  }
}

// ---------------- S4 FFT convolution + D*u + GELU ----------------------------
__global__ __launch_bounds__(256) void s4conv_k(
    const u16* __restrict__ zT, const float2* __restrict__ Kd,
    const float* __restrict__ dpar, u16* __restrict__ yT)
{
  __shared__ float2 cx[CXSZ];
  const int t = threadIdx.x;
  const int wg = blockIdx.x;          // 8 pairs * 512 channels
  const int h = wg & 511, bp = wg >> 9;
  const u16* r1 = zT + ((size_t)(2*bp) * DH + h) * SL;
  const u16* r2 = r1 + (size_t)DH * SL;
  float ur1[8], ur2[8];
  float re[16], im[16];
#pragma unroll
  for (int j = 0; j < 8; j++){
    ur1[j] = bf2f(r1[t + 256*j]);
    ur2[j] = bf2f(r2[t + 256*j]);
    re[j] = ur1[j]; im[j] = ur2[j];
  }
#pragma unroll
  for (int j = 8; j < 16; j++){ re[j] = 0.f; im[j] = 0.f; }

  fwd4096(re, im, cx, t);

  const float2* kp = Kd + (size_t)h * 4096 + 16*t;
#pragma unroll
  for (int k = 0; k < 16; k += 2){
    float4 w2 = *(const float4*)(kp + k);
    cmulw(re[k],   im[k],   w2.x, w2.y);
    cmulw(re[k+1], im[k+1], w2.z, w2.w);
  }

  inv4096(re, im, cx, t);

  const float Dv = dpar[h];
  u16* y1 = yT + ((size_t)(2*bp) * DH + h) * SL;
  u16* y2 = y1 + (size_t)DH * SL;
#pragma unroll
  for (int j = 0; j < 8; j++){
    float v1 = fmaf(re[j], (1.0f/4096.f), Dv * ur1[j]);
    float v2 = fmaf(im[j], (1.0f/4096.f), Dv * ur2[j]);
    y1[t + 256*j] = f2bf(gelu_fast(v1));
    y2[t + 256*j] = f2bf(gelu_fast(v2));
  }
}

// ---------------- layer GEMM: A = yT bf16 [K][M] batched ---------------------
// A-tile: gload_lds into linear LDS arranged as 64 subtiles of 4k x 16m
// (subtile order s = mb*8 + (kb&1)*4 + (kb>>1)); the transpose-to-fragment is
// done by ds_read_b64_tr_b16 (lane l gets col l&15, rows of window (l>>4)).
// B-tile: granule layout G(r,g) = (r<<2)|((g^r^(r>>2))&3), gload_lds.
__global__ __launch_bounds__(256) void gemm_at_k(
    const u16* __restrict__ A, const u16* __restrict__ Wt,
    const float* __restrict__ bias,
    const u16* __restrict__ resid, u16* __restrict__ Cout,
    int Mb, int N)
{
  __shared__ u16 As[4096];   // 8KB: 64 subtiles x 128B
  __shared__ u16 Bs[4096];
  const int t = threadIdx.x;
  const int n0 = blockIdx.x * 128, m0 = blockIdx.y * 128, bb = blockIdx.z;
  const int lane = t & 63, wv = t >> 6;
  const int wm = (wv >> 1) * 64, wn = (wv & 1) * 64;
  const int wbase = t & 192;
  f32x4 acc[4][4];
#pragma unroll
  for (int mi = 0; mi < 4; mi++)
#pragma unroll
    for (int ni = 0; ni < 4; ni++) acc[mi][ni] = {0.f, 0.f, 0.f, 0.f};

  // decode per-thread A-source (k,m) for its 2 granules (G = t, 256+t)
  int kA[2], mA[2];
#pragma unroll
  for (int i = 0; i < 2; i++){
    const int G = i*256 + t;
    const int s = G >> 3, r8 = G & 7;
    const int q = s & 7;
    const int kb = ((q & 3) << 1) | (q >> 2);
    kA[i] = kb*4 + (r8 >> 1);
    mA[i] = (s >> 3)*16 + (r8 & 1)*8;
  }
  const size_t Abase = (size_t)bb * DH * (size_t)Mb;   // yT [b][k=h][m=l]
  const unsigned lds_as =
      (unsigned)(unsigned long long)(__attribute__((address_space(3))) u16*)As;

  for (int k0 = 0; k0 < KDIM; k0 += 32){
    __syncthreads();
#pragma unroll
    for (int i = 0; i < 2; i++)
      gload16(A + Abase + (size_t)(k0 + kA[i]) * Mb + m0 + mA[i],
              As + (size_t)(i*256 + wbase) * 8);
#pragma unroll
    for (int i = 0; i < 2; i++){
      const int G = i*256 + t;
      const int r = G >> 2;
      const int g = ((G & 3) ^ r ^ (r >> 2)) & 3;
      gload16(Wt + (size_t)(n0 + r) * KDIM + k0 + g*8,
              Bs + (size_t)(i*256 + wbase) * 8);
    }
    __syncthreads();

    // A fragments via hardware transpose read
    uint2v ra[4], rb[4];
#pragma unroll
    for (int mi = 0; mi < 4; mi++){
      const unsigned b = lds_as + (unsigned)(((wm >> 4) + mi) * 1024 + lane * 8);
      asm volatile("ds_read_b64_tr_b16 %0, %1" : "=v"(ra[mi]) : "v"(b));
      asm volatile("ds_read_b64_tr_b16 %0, %1 offset:512" : "=v"(rb[mi]) : "v"(b));
    }
    asm volatile("s_waitcnt lgkmcnt(0)" ::: "memory");
    __builtin_amdgcn_sched_barrier(0);

    short8v af[4], bf[4];
#pragma unroll
    for (int mi = 0; mi < 4; mi++){
      union { uint2v u2[2]; short8v s8; } cvt;
      cvt.u2[0] = ra[mi]; cvt.u2[1] = rb[mi];
      af[mi] = cvt.s8;
    }
    const int fr = lane & 15, g4 = lane >> 4;
#pragma unroll
    for (int ni = 0; ni < 4; ni++){
      const int r = wn + ni*16 + fr;
      bf[ni] = *(const short8v*)&Bs[(size_t)((r<<2) | ((g4 ^ r ^ (r>>2)) & 3)) * 8];
    }
#pragma unroll
    for (int mi = 0; mi < 4; mi++)
#pragma unroll
      for (int ni = 0; ni < 4; ni++)
        acc[mi][ni] = __builtin_amdgcn_mfma_f32_16x16x32_bf16(af[mi], bf[ni], acc[mi][ni], 0, 0, 0);
  }

  const int fr = lane & 15;
  const int rq = (lane >> 4) * 4;
#pragma unroll
  for (int mi = 0; mi < 4; mi++){
#pragma unroll
    for (int ni = 0; ni < 4; ni++){
      const int gn = n0 + wn + ni*16 + fr;
      const float bs = bias[gn];
#pragma unroll
      for (int q = 0; q < 4; q++){
        const int gm = m0 + wm + mi*16 + rq + q;
        const size_t idx = ((size_t)bb * Mb + gm) * N + gn;
        Cout[idx] = f2bf(acc[mi][ni][q] + bs + bf2f(resid[idx]));
      }
    }
  }
}

// ---------------- enc/dec GEMM: granule layout + global_load_lds -------------
// AMODE: 0 = bf16 [M][K] (gload); 2 = f32 [M][K] (reg convert). No residual.
template<int AMODE, bool OUTBF>
__global__ __launch_bounds__(256) void gemm_k(
    const void* __restrict__ Aptr, const u16* __restrict__ Wt,
    const float* __restrict__ bias, void* __restrict__ Coutv,
    int Mb, int N)
{
  __shared__ u16 As[4096];   // 512 granules
  __shared__ u16 Bs[4096];
  const int t = threadIdx.x;
  const int n0 = blockIdx.x * 128, m0 = blockIdx.y * 128;
  const int lane = t & 63, wv = t >> 6;
  const int wm = (wv >> 1) * 64, wn = (wv & 1) * 64;
  const int wbase = t & 192;           // wave granule base
  f32x4 acc[4][4];
#pragma unroll
  for (int mi = 0; mi < 4; mi++)
#pragma unroll
    for (int ni = 0; ni < 4; ni++) acc[mi][ni] = {0.f, 0.f, 0.f, 0.f};

  const u16*  Ab = (const u16*)Aptr;
  const float* Af = (const float*)Aptr;

  for (int k0 = 0; k0 < KDIM; k0 += 32){
    __syncthreads();
    if (AMODE == 0){
#pragma unroll
      for (int i = 0; i < 2; i++){
        const int G = i*256 + t;
        const int r = G >> 2;
        const int g = ((G & 3) ^ r ^ (r >> 2)) & 3;
        gload16(Ab + (size_t)(m0 + r) * KDIM + k0 + g*8,
                As + (size_t)(i*256 + wbase) * 8);
      }
    } else {
      const int r = t >> 1, kh = (t & 1) << 4;
      const float* sf = Af + (size_t)(m0 + r) * KDIM + k0 + kh;
      float4 f0 = *(const float4*)sf,     f1 = *(const float4*)(sf + 4);
      float4 f2 = *(const float4*)(sf+8), f3 = *(const float4*)(sf + 12);
      ushort8v v0, v1;
      v0[0]=f2bf(f0.x); v0[1]=f2bf(f0.y); v0[2]=f2bf(f0.z); v0[3]=f2bf(f0.w);
      v0[4]=f2bf(f1.x); v0[5]=f2bf(f1.y); v0[6]=f2bf(f1.z); v0[7]=f2bf(f1.w);
      v1[0]=f2bf(f2.x); v1[1]=f2bf(f2.y); v1[2]=f2bf(f2.z); v1[3]=f2bf(f2.w);
      v1[4]=f2bf(f3.x); v1[5]=f2bf(f3.y); v1[6]=f2bf(f3.z); v1[7]=f2bf(f3.w);
      const int key = (r ^ (r >> 2)) & 3;
      *(ushort8v*)&As[(size_t)((r<<2) | ((kh>>3) ^ key))*8]       = v0;
      *(ushort8v*)&As[(size_t)((r<<2) | (((kh>>3)+1) ^ key))*8]   = v1;
    }
#pragma unroll
    for (int i = 0; i < 2; i++){
      const int G = i*256 + t;
      const int r = G >> 2;
      const int g = ((G & 3) ^ r ^ (r >> 2)) & 3;
      gload16(Wt + (size_t)(n0 + r) * KDIM + k0 + g*8,
              Bs + (size_t)(i*256 + wbase) * 8);
    }
    __syncthreads();

    const int fr = lane & 15, g4 = lane >> 4;
    short8v af[4], bf[4];
#pragma unroll
    for (int mi = 0; mi < 4; mi++){
      const int r = wm + mi*16 + fr;
      af[mi] = *(const short8v*)&As[(size_t)((r<<2) | ((g4 ^ r ^ (r>>2)) & 3)) * 8];
    }
#pragma unroll
    for (int ni = 0; ni < 4; ni++){
      const int r = wn + ni*16 + fr;
      bf[ni] = *(const short8v*)&Bs[(size_t)((r<<2) | ((g4 ^ r ^ (r>>2)) & 3)) * 8];
    }
#pragma unroll
    for (int mi = 0; mi < 4; mi++)
#pragma unroll
      for (int ni = 0; ni < 4; ni++)
        acc[mi][ni] = __builtin_amdgcn_mfma_f32_16x16x32_bf16(af[mi], bf[ni], acc[mi][ni], 0, 0, 0);
  }

  const int fr = lane & 15;
  const int rq = (lane >> 4) * 4;
#pragma unroll
  for (int mi = 0; mi < 4; mi++){
#pragma unroll
    for (int ni = 0; ni < 4; ni++){
      const int gn = n0 + wn + ni*16 + fr;
      const float bs = bias[gn];
#pragma unroll
      for (int q = 0; q < 4; q++){
        const int gm = m0 + wm + mi*16 + rq + q;
        const size_t idx = (size_t)gm * N + gn;
        float v = acc[mi][ni][q] + bs;
        if (OUTBF) ((u16*)Coutv)[idx] = f2bf(v);
        else       ((float*)Coutv)[idx] = v;
      }
    }
  }
}

// ---------------- in-place log-softmax over rows of 256 ----------------------
__global__ __launch_bounds__(256) void lsm_k(float* __restrict__ o){
  const int row = blockIdx.x * 4 + (threadIdx.x >> 6);
  const int lane = threadIdx.x & 63;
  float* p = o + (size_t)row * NDO + lane * 4;
  float4 v = *(const float4*)p;
  float mx = fmaxf(fmaxf(v.x, v.y), fmaxf(v.z, v.w));
#pragma unroll
  for (int q = 32; q; q >>= 1) mx = fmaxf(mx, __shfl_xor(mx, q));
  float e = __expf(v.x - mx) + __expf(v.y - mx) + __expf(v.z - mx) + __expf(v.w - mx);
#pragma unroll
  for (int q = 32; q; q >>= 1) e += __shfl_xor(e, q);
  const float lse = mx + __logf(e);
  v.x -= lse; v.y -= lse; v.z -= lse; v.w -= lse;
  *(float4*)p = v;
}

// ---------------- launcher ----------------------------------------------------
extern "C" void kernel_launch(void* const* d_in, const int* in_sizes, int n_in,
                              void* d_out, int out_size, void* d_ws, size_t ws_size,
                              hipStream_t stream)
{
  (void)in_sizes; (void)n_in; (void)out_size; (void)ws_size;
  const float* x      = (const float*)d_in[0];
  const float* enc_w  = (const float*)d_in[1];
  const float* enc_b  = (const float*)d_in[2];
  const float* dec_w  = (const float*)d_in[3];
  const float* dec_b  = (const float*)d_in[4];
  const float* ln_s   = (const float*)d_in[5];
  const float* ln_b   = (const float*)d_in[6];
  const float* lam_re = (const float*)d_in[7];
  const float* lam_im = (const float*)d_in[8];
  const float* p_re   = (const float*)d_in[9];
  const float* p_im   = (const float*)d_in[10];
  const float* b_re   = (const float*)d_in[11];
  const float* b_im   = (const float*)d_in[12];
  const float* c_re   = (const float*)d_in[13];
  const float* c_im   = (const float*)d_in[14];
  const float* lstep  = (const float*)d_in[15];
  const float* d_par  = (const float*)d_in[16];
  const float* out_w  = (const float*)d_in[17];
  const float* out_b  = (const float*)d_in[18];

  char* ws = (char*)d_ws;
  u16*    hbuf = (u16*)(ws);
  u16*    zT   = (u16*)  (ws + (size_t)67108864 + 33554432);
  u16*    yT   = (u16*)  (ws + (size_t)67108864 + 2*33554432);
  float2* Kd   = (float2*)(ws + (size_t)67108864 + 3*33554432);
  u16*    Wt   = (u16*)  (ws + (size_t)67108864 + 3*33554432 + 67108864);
  u16*    WtEnc = Wt;                         // 512*512
  u16*    WtOut = Wt + 262144;                // 4 * 512*512
  u16*    WtDec = Wt + 262144*5;              // 256*512
  float*  outp = (float*)d_out;

  // Cauchy weights live in d_out scratch (overwritten by dec gemm at the end)
  float4* cwA = (float4*)d_out;               // 131072 float4
  float4* cwB = cwA + 131072;
  float*  cwS = (float*)(cwB + 131072);

  // 1) weight prep
  prep_k<<<dim3(NLAY*DH*NST/256), 256, 0, stream>>>(lam_re, lam_im, p_re, p_im,
                                                    b_re, b_im, c_re, c_im, cwA, cwB, cwS);
  wconv_k<<<dim3(8, 8, 1), 256, 0, stream>>>(enc_w, WtEnc, KDIM, DH);
  wconv_k<<<dim3(8, 8, NLAY), 256, 0, stream>>>(out_w, WtOut, KDIM, DH);
  wconv_k<<<dim3(8, 4, 1), 256, 0, stream>>>(dec_w, WtDec, KDIM, NDO);
  // 2) DPLR kernels
  cauchy_k<<<dim3(4, DH, NLAY), 256, 0, stream>>>(cwA, cwB, cwS, lstep, Kd);
  kdfft_k<<<dim3(NLAY*DH), 256, 0, stream>>>(Kd);
  // 3) encoder GEMM: h = x @ enc_w + enc_b  (f32 A in, bf16 out)
  gemm_k<2,true><<<dim3(DH/128, BL/128, 1), 256, 0, stream>>>(
      x, WtEnc, enc_b, hbuf, BL, DH);
  // 4) layers
  for (int i = 0; i < NLAY; i++){
    lnt_k<<<dim3(SL/LTILE, NB), 256, 0, stream>>>(hbuf, ln_s + i*DH, ln_b + i*DH, zT);
    s4conv_k<<<dim3((NB/2)*DH), 256, 0, stream>>>(
        zT, Kd + (size_t)i*DH*4096, d_par + i*DH, yT);
    gemm_at_k<<<dim3(DH/128, SL/128, NB), 256, 0, stream>>>(
        yT, WtOut + (size_t)i*262144, out_b + i*DH, hbuf, hbuf, SL, DH);
  }
  // 5) decoder (bf16 A in, f32 out) + log_softmax
  gemm_k<0,false><<<dim3(NDO/128, BL/128, 1), 256, 0, stream>>>(
      hbuf, WtDec, dec_b, outp, BL, NDO);
  lsm_k<<<dim3(BL/4), 256, 0, stream>>>(outp);
}

// Round 11
// 707.203 us; speedup vs baseline: 1.1759x; 1.0351x over previous
//
#include <hip/hip_runtime.h>
#include <hip/hip_bf16.h>

// ---------------- problem constants ----------------
#define NLAY 4
#define DH   512
#define NST  64
#define NB   16
#define SL   2048
#define NDO  256
#define BL   (NB*SL)      // 32768 rows
#define KDIM 512
#define TWOPI 6.283185307179586476925287

typedef unsigned short u16;
typedef __attribute__((ext_vector_type(8))) short  short8v;   // 8 bf16 (4 VGPR) MFMA frag
typedef __attribute__((ext_vector_type(8))) unsigned short ushort8v;
typedef __attribute__((ext_vector_type(4))) float  f32x4;
typedef __attribute__((ext_vector_type(2))) unsigned int uint2v;

#define RCPF(x) __builtin_amdgcn_rcpf(x)

// ---------------- small helpers ----------------
__device__ __forceinline__ float bf2f(u16 v){
  union { unsigned u; float f; } x; x.u = ((unsigned)v) << 16; return x.f;
}
__device__ __forceinline__ u16 f2bf(float f){
  union { float f; unsigned u; } x; x.f = f;
  unsigned u = x.u;
  unsigned r = u + 0x7fffu + ((u >> 16) & 1u);   // RNE
  return (u16)(r >> 16);
}
__device__ __forceinline__ void cmulw(float& xr, float& xi, float wr, float wi){
  float tr = xr*wr - xi*wi;
  xi = fmaf(xr, wi, xi*wr);
  xr = tr;
}
__device__ __forceinline__ float gelu_fast(float v){
  const float c0 = 0.7978845608028654f;
  float u = c0 * fmaf(0.044715f, v*v*v, v);
  return v * RCPF(1.0f + __expf(-2.0f * u));
}
// async global(16B/lane) -> LDS (wave-uniform base + lane*16, HW-linear)
__device__ __forceinline__ void gload16(const void* g, void* l){
  __builtin_amdgcn_global_load_lds(
      (__attribute__((address_space(1))) void*)(g),
      (__attribute__((address_space(3))) void*)(l), 16, 0, 0);
}

// apply w^k twiddles (w = e^{i a}) to slots k=1..15 via power recurrence:
// one hw sincos + 14 full-rate complex muls instead of 30 quarter-rate trans.
__device__ __forceinline__ void twapply(float* re, float* im, float a){
  float ci, cr;
  __sincosf(a, &ci, &cr);
  float wr = cr, wi = ci;
#pragma unroll
  for (int k = 1; k < 16; k++){
    cmulw(re[k], im[k], wr, wi);
    const float nr = wr*cr - wi*ci;
    wi = fmaf(wr, ci, wi*cr);
    wr = nr;
  }
}

// ---------------- DFT-16 in registers (radix-4 x radix-4), natural in/out ----
template<int SGN>
__device__ __forceinline__ void dft4w(float& r0, float& i0, float& r1, float& i1,
                                      float& r2, float& i2, float& r3, float& i3){
  const float t0r = r0 + r2, t0i = i0 + i2;
  const float t1r = r0 - r2, t1i = i0 - i2;
  const float t2r = r1 + r3, t2i = i1 + i3;
  const float t3r = r1 - r3, t3i = i1 - i3;
  r0 = t0r + t2r; i0 = t0i + t2i;
  r2 = t0r - t2r; i2 = t0i - t2i;
  if (SGN < 0){ r1 = t1r + t3i; i1 = t1i - t3r; r3 = t1r - t3i; i3 = t1i + t3r; }
  else        { r1 = t1r - t3i; i1 = t1i + t3r; r3 = t1r + t3i; i3 = t1i - t3r; }
}

template<int SGN>
__device__ __forceinline__ void dft16(float* re, float* im){
#pragma unroll
  for (int b = 0; b < 4; b++)
    dft4w<SGN>(re[b], im[b], re[4+b], im[4+b], re[8+b], im[8+b], re[12+b], im[12+b]);
  const float C1 = 0.92387953251128675613f, S1_ = 0.38268343236508977172f;
  const float C2 = 0.70710678118654752440f;
  const float sg = (SGN < 0) ? -1.f : 1.f;
  cmulw(re[5],  im[5],   C1,  sg*S1_);
  cmulw(re[9],  im[9],   C2,  sg*C2);
  cmulw(re[13], im[13],  S1_, sg*C1);
  cmulw(re[6],  im[6],   C2,  sg*C2);
  cmulw(re[10], im[10],  0.f, sg*1.f);
  cmulw(re[14], im[14], -C2,  sg*C2);
  cmulw(re[7],  im[7],   S1_, sg*C1);
  cmulw(re[11], im[11], -C2,  sg*C2);
  cmulw(re[15], im[15], -C1,  sg*(-S1_));
#pragma unroll
  for (int c = 0; c < 4; c++)
    dft4w<SGN>(re[4*c], im[4*c], re[4*c+1], im[4*c+1], re[4*c+2], im[4*c+2], re[4*c+3], im[4*c+3]);
  float tr_, ti_;
#define SWP(A,B) tr_=re[A]; re[A]=re[B]; re[B]=tr_; ti_=im[A]; im[A]=im[B]; im[B]=ti_;
  SWP(1,4) SWP(2,8) SWP(3,12) SWP(6,9) SWP(7,13) SWP(11,14)
#undef SWP
}

// LDS padding: all three stage patterns <=2-way bank conflicts
__device__ __forceinline__ int cxpad(int i){ return i + (i >> 4) + ((i >> 8) << 1); }
#define CXSZ 4384

// forward 4096-pt DIF radix-16 (float2 LDS, 2 barriers total).
// The exchange-2 store set of thread t == its own exchange-1 read set
// (address a=b2+16j <-> unique t), and stores are data-dependent on the
// reads -> no barrier needed between read-1 and store-2 (R3/R4-proven).
__device__ __forceinline__ void fwd4096(float* re, float* im, float2* cx, int t){
  dft16<-1>(re, im);
  twapply(re, im, -(float)(TWOPI/4096.0) * (float)t);
#pragma unroll
  for (int k = 0; k < 16; k++) cx[cxpad(t + 256*k)] = make_float2(re[k], im[k]);
  __syncthreads();
  const int k1 = t >> 4, m2 = t & 15;
  const int b2 = k1*256 + m2;
#pragma unroll
  for (int j = 0; j < 16; j++){ float2 v = cx[cxpad(b2 + 16*j)]; re[j] = v.x; im[j] = v.y; }
  dft16<-1>(re, im);
  twapply(re, im, -(float)(TWOPI/256.0) * (float)m2);
#pragma unroll
  for (int k = 0; k < 16; k++) cx[cxpad(b2 + 16*k)] = make_float2(re[k], im[k]);
  __syncthreads();
#pragma unroll
  for (int j = 0; j < 16; j++){ float2 v = cx[cxpad(16*t + j)]; re[j] = v.x; im[j] = v.y; }
  dft16<-1>(re, im);
}

// inverse: input = values at positions 16t+k3, output time y[t+256j] (unscaled)
__device__ __forceinline__ void inv4096(float* re, float* im, float2* cx, int t){
  dft16<1>(re, im);
#pragma unroll
  for (int j = 0; j < 16; j++) cx[cxpad(16*t + j)] = make_float2(re[j], im[j]);
  __syncthreads();
  const int k1 = t >> 4, m2 = t & 15;
  const int b2 = k1*256 + m2;
#pragma unroll
  for (int k = 0; k < 16; k++){ float2 v = cx[cxpad(b2 + 16*k)]; re[k] = v.x; im[k] = v.y; }
  twapply(re, im, (float)(TWOPI/256.0) * (float)m2);
  dft16<1>(re, im);
#pragma unroll
  for (int j = 0; j < 16; j++) cx[cxpad(b2 + 16*j)] = make_float2(re[j], im[j]);
  __syncthreads();
#pragma unroll
  for (int k = 0; k < 16; k++){ float2 v = cx[cxpad(t + 256*k)]; re[k] = v.x; im[k] = v.y; }
  twapply(re, im, (float)(TWOPI/4096.0) * (float)t);
  dft16<1>(re, im);
}

// ---------------- prep: per-(lay,h,n) Woodbury weights ----------------
__global__ __launch_bounds__(256) void prep_k(
  const float* __restrict__ lam_re, const float* __restrict__ lam_im,
  const float* __restrict__ p_re,  const float* __restrict__ p_im,
  const float* __restrict__ b_re,  const float* __restrict__ b_im,
  const float* __restrict__ c_re,  const float* __restrict__ c_im,
  float4* __restrict__ cwA, float4* __restrict__ cwB, float* __restrict__ cwS)
{
  const int i = blockIdx.x * 256 + threadIdx.x;   // < NLAY*DH*NST
  const float lr = lam_re[i], li = lam_im[i];
  const float pr = p_re[i],  pi = p_im[i];
  const float br = b_re[i],  bi = b_im[i];
  const float cr = c_re[i],  ci = c_im[i];
  cwA[i] = make_float4(lr, li, cr*br + ci*bi, cr*bi - ci*br);                  // Lam, conj(C)*B
  cwB[i] = make_float4(cr*pr + ci*pi, cr*pi - ci*pr, pr*br + pi*bi, pr*bi - pi*br); // cC*P, cP*B
  cwS[i] = pr*pr + pi*pi;                                                      // conj(P)*P (real)
}

// ---------------- Cauchy/Woodbury generating function -> at_roots -----------
// g = i*gi with gi = (2/step)*tan(theta/2);  c = 1 + i*tan(theta/2).
// 2 freqs per thread (lb, lb+1024). Near its VALU floor (~122 us) — frozen.
__global__ __launch_bounds__(256) void cauchy_k(
    const float4* __restrict__ cwA, const float4* __restrict__ cwB,
    const float* __restrict__ cwS, const float* __restrict__ lstep,
    float2* __restrict__ Kd)
{
  const int t = threadIdx.x;
  const int h = blockIdx.y, lay = blockIdx.z;
  const int lb = blockIdx.x * 256 + t;           // [0, 1024)
  const int wb = (lay*DH + h) * NST;
  const float tw0 = 2.0f * expf(-lstep[lay*DH + h]);   // 2/step

  float T0,T1, g0,g1;
  { float sn, cs;
    sincosf((float)(TWOPI/4096.0)*(float)(lb       ), &sn, &cs); T0 = sn*RCPF(cs); g0 = tw0*T0;
    sincosf((float)(TWOPI/4096.0)*(float)(lb + 1024), &sn, &cs); T1 = sn*RCPF(cs); g1 = tw0*T1;
  }

  float k00r0=0,k00i0=0,k01r0=0,k01i0=0,k10r0=0,k10i0=0,k11r0=0,k11i0=0;
  float k00r1=0,k00i1=0,k01r1=0,k01i1=0,k10r1=0,k10i1=0,k11r1=0,k11i1=0;

#pragma unroll 2
  for (int n = 0; n < NST; n++){
    const float4 A  = cwA[wb + n];
    const float4 Bv = cwB[wb + n];
    const float w11 = cwS[wb + n];
    const float nlr = -A.x;            // -lam_re  (real part of g - Lam)
    const float dr2 = A.x * A.x;
#define CSTEP(J) { \
    const float di = g##J - A.y; \
    const float sI = RCPF(fmaf(di, di, dr2)); \
    const float ivr = nlr * sI, ivi = -di * sI; \
    k00r##J = fmaf(A.z,  ivr, fmaf(-A.w,  ivi, k00r##J)); \
    k00i##J = fmaf(A.z,  ivi, fmaf( A.w,  ivr, k00i##J)); \
    k01r##J = fmaf(Bv.x, ivr, fmaf(-Bv.y, ivi, k01r##J)); \
    k01i##J = fmaf(Bv.x, ivi, fmaf( Bv.y, ivr, k01i##J)); \
    k10r##J = fmaf(Bv.z, ivr, fmaf(-Bv.w, ivi, k10r##J)); \
    k10i##J = fmaf(Bv.z, ivi, fmaf( Bv.w, ivr, k10i##J)); \
    k11r##J = fmaf(w11,  ivr, k11r##J); \
    k11i##J = fmaf(w11,  ivi, k11i##J); }
    CSTEP(0) CSTEP(1)
#undef CSTEP
  }

  float2* kp = Kd + (size_t)(lay*DH + h) * 4096;
#define COUT(J, LOFF) { \
    const float d1r = 1.f + k11r##J, d1i = k11i##J; \
    const float idn = RCPF(fmaf(d1r, d1r, d1i*d1i)); \
    const float wr = k01r##J*k10r##J - k01i##J*k10i##J; \
    const float wi = k01r##J*k10i##J + k01i##J*k10r##J; \
    const float vr = fmaf(wr, d1r,  wi*d1i) * idn; \
    const float vi = fmaf(wi, d1r, -wr*d1i) * idn; \
    const float sr = k00r##J - vr, si = k00i##J - vi; \
    kp[lb + LOFF] = make_float2(fmaf(-T##J, si, sr), fmaf(T##J, sr, si)); }
  COUT(0, 0) COUT(1, 1024)
#undef COUT
}

// ---------------- ifft2048 + fwd fft4096 -> Kd (digit-rev order) -------------
__global__ __launch_bounds__(256) void kdfft_k(float2* __restrict__ Kd){
  __shared__ float  ar[SL], ai[SL];
  __shared__ float2 cx[CXSZ];
  const int t = threadIdx.x;
  const size_t base = (size_t)blockIdx.x * 4096;
#pragma unroll
  for (int q = 0; q < 8; q++){
    const int l = t + 256*q;
    float2 v = Kd[base + l];
    const int brv = __brev((unsigned)l) >> 21;    // 11-bit reverse
    ar[brv] = v.x; ai[brv] = v.y;
  }
  __syncthreads();

  // inverse DFT-2048 (radix-2 DIT, bit-reversed input -> natural K)
  for (int s = 0; s < 11; s++){
    const int half = 1 << s;
    const float fac = (float)(TWOPI) / (float)(2 << s);
#pragma unroll
    for (int q = 0; q < 4; q++){
      const int v = t + 256*q;
      const int pos = v & (half - 1);
      const int i0 = ((v >> s) << (s+1)) + pos;
      const int i1 = i0 + half;
      const float ang = fac * (float)pos;
      const float wc = __cosf(ang), ws = __sinf(ang);   // e^{+i ang}
      const float xr = ar[i1], xi = ai[i1];
      const float tr = wc*xr - ws*xi, ti = fmaf(wc, xi, ws*xr);
      const float ur_ = ar[i0], ui_ = ai[i0];
      ar[i0] = ur_ + tr; ai[i0] = ui_ + ti;
      ar[i1] = ur_ - tr; ai[i1] = ui_ - ti;
    }
    __syncthreads();
  }

  // K (real, scaled 1/2048), zero-pad to 4096, forward DIF -> Kd
  float re[16], im[16];
#pragma unroll
  for (int j = 0; j < 16; j++){
    re[j] = (j < 8) ? ar[t + 256*j] * (1.0f/2048.f) : 0.f;
    im[j] = 0.f;
  }
  fwd4096(re, im, cx, t);
  float2* kp = Kd + base + 16*t;
#pragma unroll
  for (int k = 0; k < 16; k += 2)
    *(float4*)(kp + k) = make_float4(re[k], im[k], re[k+1], im[k+1]);
}

// ---------------- weight convert+transpose f32[K][N] -> bf16[N][K] -----------
// one launch: z=0 enc, z=1..4 out_w layers, z=5 dec (y<4 only).
__global__ __launch_bounds__(256) void wconv_all_k(
    const float* __restrict__ enc_w, const float* __restrict__ out_w,
    const float* __restrict__ dec_w, u16* __restrict__ Wt)
{
  const int z = blockIdx.z;
  const float* src; u16* dst; int N;
  if (z == 0){ src = enc_w; dst = Wt; N = DH; }
  else if (z <= 4){ src = out_w + (size_t)(z-1)*KDIM*DH; dst = Wt + (size_t)z*262144; N = DH; }
  else { if (blockIdx.y >= 4) return; src = dec_w; dst = Wt + (size_t)5*262144; N = NDO; }
  __shared__ u16 tile[64][72];
  const int k0 = blockIdx.x * 64, n0 = blockIdx.y * 64;
  const int r = threadIdx.x >> 2, c4 = (threadIdx.x & 3) * 16;
  const float* s = src + (size_t)(k0 + r) * N + n0 + c4;
  float4 f0 = *(const float4*)s, f1 = *(const float4*)(s+4);
  float4 f2 = *(const float4*)(s+8), f3 = *(const float4*)(s+12);
  tile[c4+0][r]=f2bf(f0.x); tile[c4+1][r]=f2bf(f0.y); tile[c4+2][r]=f2bf(f0.z); tile[c4+3][r]=f2bf(f0.w);
  tile[c4+4][r]=f2bf(f1.x); tile[c4+5][r]=f2bf(f1.y); tile[c4+6][r]=f2bf(f1.z); tile[c4+7][r]=f2bf(f1.w);
  tile[c4+8][r]=f2bf(f2.x); tile[c4+9][r]=f2bf(f2.y); tile[c4+10][r]=f2bf(f2.z); tile[c4+11][r]=f2bf(f2.w);
  tile[c4+12][r]=f2bf(f3.x); tile[c4+13][r]=f2bf(f3.y); tile[c4+14][r]=f2bf(f3.z); tile[c4+15][r]=f2bf(f3.w);
  __syncthreads();
  u16* d = dst + (size_t)(n0 + r) * KDIM + k0 + c4;
  *(ushort8v*)d       = *(const ushort8v*)&tile[r][c4];
  *(ushort8v*)(d + 8) = *(const ushort8v*)&tile[r][c4 + 8];
}

// ---------------- fused LayerNorm + transpose: bf16 [b,l,h] -> bf16 [b,h,l] --
#define LTILE 32
__device__ __forceinline__ int lnswz(int h){ return ((h >> 1) + (h >> 6)) & 3; }

__global__ __launch_bounds__(256) void lnt_k(const u16* __restrict__ hsrc,
    const float* __restrict__ gam, const float* __restrict__ bet,
    u16* __restrict__ zT){
  __shared__ u16 tile[DH][LTILE];
  __shared__ float smu[LTILE], srs[LTILE];
  const int t = threadIdx.x;
  const int b = blockIdx.y, l0 = blockIdx.x * LTILE;
  const int r = t >> 3, hb = (t & 7) * 64;
  const u16* p = hsrc + ((size_t)b * SL + l0 + r) * DH + hb;
  float s = 0.f, sq = 0.f;
#pragma unroll
  for (int j8 = 0; j8 < 8; j8++){
    ushort8v w = *(const ushort8v*)(p + j8*8);
    const int h0 = hb + j8*8;
#pragma unroll
    for (int d = 0; d < 8; d++){
      const float f = bf2f((u16)w[d]);
      s += f; sq = fmaf(f, f, sq);
      tile[h0+d][r ^ (lnswz(h0+d) << 3)] = (u16)w[d];
    }
  }
  s  += __shfl_xor(s, 1);  sq += __shfl_xor(sq, 1);
  s  += __shfl_xor(s, 2);  sq += __shfl_xor(sq, 2);
  s  += __shfl_xor(s, 4);  sq += __shfl_xor(sq, 4);
  if ((t & 7) == 0){
    const float mu = s * (1.0f/DH);
    smu[r] = mu;
    srs[r] = rsqrtf(sq * (1.0f/DH) - mu*mu + 1e-6f);
  }
  __syncthreads();

#pragma unroll
  for (int hh = 0; hh < 2; hh++){
    const int h = t + hh*256;
    const float g = gam[h], be = bet[h];
    const int sw = lnswz(h);
    u16* dst = zT + ((size_t)b * DH + h) * SL + l0;
#pragma unroll
    for (int og = 0; og < 4; og++){
      const int lg = og ^ sw;
      ushort8v v = *(const ushort8v*)&tile[h][og*8];
      const float4 m0 = *(const float4*)&smu[lg*8];
      const float4 m1 = *(const float4*)&smu[lg*8 + 4];
      const float4 r0 = *(const float4*)&srs[lg*8];
      const float4 r1 = *(const float4*)&srs[lg*8 + 4];
      ushort8v o;
      o[0] = f2bf(fmaf(bf2f((u16)v[0]) - m0.x, r0.x*g, be));
      o[1] = f2bf(fmaf(bf2f((u16)v[1]) - m0.y, r0.y*g, be));
      o[2] = f2bf(fmaf(bf2f((u16)v[2]) - m0.z, r0.z*g, be));
      o[3] = f2bf(fmaf(bf2f((u16)v[3]) - m0.w, r0.w*g, be));
      o[4] = f2bf(fmaf(bf2f((u16)v[4]) - m1.x, r1.x*g, be));
      o[5] = f2bf(fmaf(bf2f((u16)v[5]) - m1.y, r1.y*g, be));
      o[6] = f2bf(fmaf(bf2f((u16)v[6]) - m1.z, r1.z*g, be));
      o[7] = f2bf(fmaf(bf2f((u16)v[7]) - m1.w, r1.w*g, be));
      *(ushort8v*)(dst + lg*8) = o;
    }
  }
}

// ---------------- S4 FFT convolution + D*u + GELU ----------------------------
__global__ __launch_bounds__(256) void s4conv_k(
    const u16* __restrict__ zT, const float2* __restrict__ Kd,
    const float* __restrict__ dpar, u16* __restrict__ yT)
{
  __shared__ float2 cx[CXSZ];
  const int t = threadIdx.x;
  const int wg = blockIdx.x;          // 8 pairs * 512 channels
  const int h = wg & 511, bp = wg >> 9;
  const u16* r1 = zT + ((size_t)(2*bp) * DH + h) * SL;
  const u16* r2 = r1 + (size_t)DH * SL;
  float ur1[8], ur2[8];
  float re[16], im[16];
#pragma unroll
  for (int j = 0; j < 8; j++){
    ur1[j] = bf2f(r1[t + 256*j]);
    ur2[j] = bf2f(r2[t + 256*j]);
    re[j] = ur1[j]; im[j] = ur2[j];
  }
#pragma unroll
  for (int j = 8; j < 16; j++){ re[j] = 0.f; im[j] = 0.f; }

  fwd4096(re, im, cx, t);

  const float2* kp = Kd + (size_t)h * 4096 + 16*t;
#pragma unroll
  for (int k = 0; k < 16; k += 2){
    float4 w2 = *(const float4*)(kp + k);
    cmulw(re[k],   im[k],   w2.x, w2.y);
    cmulw(re[k+1], im[k+1], w2.z, w2.w);
  }

  inv4096(re, im, cx, t);

  const float Dv = dpar[h];
  u16* y1 = yT + ((size_t)(2*bp) * DH + h) * SL;
  u16* y2 = y1 + (size_t)DH * SL;
#pragma unroll
  for (int j = 0; j < 8; j++){
    float v1 = fmaf(re[j], (1.0f/4096.f), Dv * ur1[j]);
    float v2 = fmaf(im[j], (1.0f/4096.f), Dv * ur2[j]);
    y1[t + 256*j] = f2bf(gelu_fast(v1));
    y2[t + 256*j] = f2bf(gelu_fast(v2));
  }
}

// ---------------- layer GEMM: A = yT bf16 [K][M] batched ---------------------
// A-tile: gload_lds into linear LDS arranged as 64 subtiles of 4k x 16m
// (subtile order s = mb*8 + (kb&1)*4 + (kb>>1)); the transpose-to-fragment is
// done by ds_read_b64_tr_b16 (lane l gets col l&15, rows of window (l>>4)).
// B-tile: granule layout G(r,g) = (r<<2)|((g^r^(r>>2))&3), gload_lds.
__global__ __launch_bounds__(256) void gemm_at_k(
    const u16* __restrict__ A, const u16* __restrict__ Wt,
    const float* __restrict__ bias,
    const u16* __restrict__ resid, u16* __restrict__ Cout,
    int Mb, int N)
{
  __shared__ u16 As[4096];   // 8KB: 64 subtiles x 128B
  __shared__ u16 Bs[4096];
  const int t = threadIdx.x;
  const int n0 = blockIdx.x * 128, m0 = blockIdx.y * 128, bb = blockIdx.z;
  const int lane = t & 63, wv = t >> 6;
  const int wm = (wv >> 1) * 64, wn = (wv & 1) * 64;
  const int wbase = t & 192;
  f32x4 acc[4][4];
#pragma unroll
  for (int mi = 0; mi < 4; mi++)
#pragma unroll
    for (int ni = 0; ni < 4; ni++) acc[mi][ni] = {0.f, 0.f, 0.f, 0.f};

  // decode per-thread A-source (k,m) for its 2 granules (G = t, 256+t)
  int kA[2], mA[2];
#pragma unroll
  for (int i = 0; i < 2; i++){
    const int G = i*256 + t;
    const int s = G >> 3, r8 = G & 7;
    const int q = s & 7;
    const int kb = ((q & 3) << 1) | (q >> 2);
    kA[i] = kb*4 + (r8 >> 1);
    mA[i] = (s >> 3)*16 + (r8 & 1)*8;
  }
  const size_t Abase = (size_t)bb * DH * (size_t)Mb;   // yT [b][k=h][m=l]
  const unsigned lds_as =
      (unsigned)(unsigned long long)(__attribute__((address_space(3))) u16*)As;

  for (int k0 = 0; k0 < KDIM; k0 += 32){
    __syncthreads();
#pragma unroll
    for (int i = 0; i < 2; i++)
      gload16(A + Abase + (size_t)(k0 + kA[i]) * Mb + m0 + mA[i],
              As + (size_t)(i*256 + wbase) * 8);
#pragma unroll
    for (int i = 0; i < 2; i++){
      const int G = i*256 + t;
      const int r = G >> 2;
      const int g = ((G & 3) ^ r ^ (r >> 2)) & 3;
      gload16(Wt + (size_t)(n0 + r) * KDIM + k0 + g*8,
              Bs + (size_t)(i*256 + wbase) * 8);
    }
    __syncthreads();

    // A fragments via hardware transpose read
    uint2v ra[4], rb[4];
#pragma unroll
    for (int mi = 0; mi < 4; mi++){
      const unsigned b = lds_as + (unsigned)(((wm >> 4) + mi) * 1024 + lane * 8);
      asm volatile("ds_read_b64_tr_b16 %0, %1" : "=v"(ra[mi]) : "v"(b));
      asm volatile("ds_read_b64_tr_b16 %0, %1 offset:512" : "=v"(rb[mi]) : "v"(b));
    }
    asm volatile("s_waitcnt lgkmcnt(0)" ::: "memory");
    __builtin_amdgcn_sched_barrier(0);

    short8v af[4], bf[4];
#pragma unroll
    for (int mi = 0; mi < 4; mi++){
      union { uint2v u2[2]; short8v s8; } cvt;
      cvt.u2[0] = ra[mi]; cvt.u2[1] = rb[mi];
      af[mi] = cvt.s8;
    }
    const int fr = lane & 15, g4 = lane >> 4;
#pragma unroll
    for (int ni = 0; ni < 4; ni++){
      const int r = wn + ni*16 + fr;
      bf[ni] = *(const short8v*)&Bs[(size_t)((r<<2) | ((g4 ^ r ^ (r>>2)) & 3)) * 8];
    }
#pragma unroll
    for (int mi = 0; mi < 4; mi++)
#pragma unroll
      for (int ni = 0; ni < 4; ni++)
        acc[mi][ni] = __builtin_amdgcn_mfma_f32_16x16x32_bf16(af[mi], bf[ni], acc[mi][ni], 0, 0, 0);
  }

  const int fr = lane & 15;
  const int rq = (lane >> 4) * 4;
#pragma unroll
  for (int mi = 0; mi < 4; mi++){
#pragma unroll
    for (int ni = 0; ni < 4; ni++){
      const int gn = n0 + wn + ni*16 + fr;
      const float bs = bias[gn];
#pragma unroll
      for (int q = 0; q < 4; q++){
        const int gm = m0 + wm + mi*16 + rq + q;
        const size_t idx = ((size_t)bb * Mb + gm) * N + gn;
        Cout[idx] = f2bf(acc[mi][ni][q] + bs + bf2f(resid[idx]));
      }
    }
  }
}

// ---------------- enc/dec GEMM: granule layout + global_load_lds -------------
// AMODE: 0 = bf16 [M][K] (gload); 2 = f32 [M][K] (reg convert). No residual.
template<int AMODE, bool OUTBF>
__global__ __launch_bounds__(256) void gemm_k(
    const void* __restrict__ Aptr, const u16* __restrict__ Wt,
    const float* __restrict__ bias, void* __restrict__ Coutv,
    int Mb, int N)
{
  __shared__ u16 As[4096];   // 512 granules
  __shared__ u16 Bs[4096];
  const int t = threadIdx.x;
  const int n0 = blockIdx.x * 128, m0 = blockIdx.y * 128;
  const int lane = t & 63, wv = t >> 6;
  const int wm = (wv >> 1) * 64, wn = (wv & 1) * 64;
  const int wbase = t & 192;           // wave granule base
  f32x4 acc[4][4];
#pragma unroll
  for (int mi = 0; mi < 4; mi++)
#pragma unroll
    for (int ni = 0; ni < 4; ni++) acc[mi][ni] = {0.f, 0.f, 0.f, 0.f};

  const u16*  Ab = (const u16*)Aptr;
  const float* Af = (const float*)Aptr;

  for (int k0 = 0; k0 < KDIM; k0 += 32){
    __syncthreads();
    if (AMODE == 0){
#pragma unroll
      for (int i = 0; i < 2; i++){
        const int G = i*256 + t;
        const int r = G >> 2;
        const int g = ((G & 3) ^ r ^ (r >> 2)) & 3;
        gload16(Ab + (size_t)(m0 + r) * KDIM + k0 + g*8,
                As + (size_t)(i*256 + wbase) * 8);
      }
    } else {
      const int r = t >> 1, kh = (t & 1) << 4;
      const float* sf = Af + (size_t)(m0 + r) * KDIM + k0 + kh;
      float4 f0 = *(const float4*)sf,     f1 = *(const float4*)(sf + 4);
      float4 f2 = *(const float4*)(sf+8), f3 = *(const float4*)(sf + 12);
      ushort8v v0, v1;
      v0[0]=f2bf(f0.x); v0[1]=f2bf(f0.y); v0[2]=f2bf(f0.z); v0[3]=f2bf(f0.w);
      v0[4]=f2bf(f1.x); v0[5]=f2bf(f1.y); v0[6]=f2bf(f1.z); v0[7]=f2bf(f1.w);
      v1[0]=f2bf(f2.x); v1[1]=f2bf(f2.y); v1[2]=f2bf(f2.z); v1[3]=f2bf(f2.w);
      v1[4]=f2bf(f3.x); v1[5]=f2bf(f3.y); v1[6]=f2bf(f3.z); v1[7]=f2bf(f3.w);
      const int key = (r ^ (r >> 2)) & 3;
      *(ushort8v*)&As[(size_t)((r<<2) | ((kh>>3) ^ key))*8]       = v0;
      *(ushort8v*)&As[(size_t)((r<<2) | (((kh>>3)+1) ^ key))*8]   = v1;
    }
#pragma unroll
    for (int i = 0; i < 2; i++){
      const int G = i*256 + t;
      const int r = G >> 2;
      const int g = ((G & 3) ^ r ^ (r >> 2)) & 3;
      gload16(Wt + (size_t)(n0 + r) * KDIM + k0 + g*8,
              Bs + (size_t)(i*256 + wbase) * 8);
    }
    __syncthreads();

    const int fr = lane & 15, g4 = lane >> 4;
    short8v af[4], bf[4];
#pragma unroll
    for (int mi = 0; mi < 4; mi++){
      const int r = wm + mi*16 + fr;
      af[mi] = *(const short8v*)&As[(size_t)((r<<2) | ((g4 ^ r ^ (r>>2)) & 3)) * 8];
    }
#pragma unroll
    for (int ni = 0; ni < 4; ni++){
      const int r = wn + ni*16 + fr;
      bf[ni] = *(const short8v*)&Bs[(size_t)((r<<2) | ((g4 ^ r ^ (r>>2)) & 3)) * 8];
    }
#pragma unroll
    for (int mi = 0; mi < 4; mi++)
#pragma unroll
      for (int ni = 0; ni < 4; ni++)
        acc[mi][ni] = __builtin_amdgcn_mfma_f32_16x16x32_bf16(af[mi], bf[ni], acc[mi][ni], 0, 0, 0);
  }

  const int fr = lane & 15;
  const int rq = (lane >> 4) * 4;
#pragma unroll
  for (int mi = 0; mi < 4; mi++){
#pragma unroll
    for (int ni = 0; ni < 4; ni++){
      const int gn = n0 + wn + ni*16 + fr;
      const float bs = bias[gn];
#pragma unroll
      for (int q = 0; q < 4; q++){
        const int gm = m0 + wm + mi*16 + rq + q;
        const size_t idx = (size_t)gm * N + gn;
        float v = acc[mi][ni][q] + bs;
        if (OUTBF) ((u16*)Coutv)[idx] = f2bf(v);
        else       ((float*)Coutv)[idx] = v;
      }
    }
  }
}

// ---------------- in-place log-softmax over rows of 256 ----------------------
__global__ __launch_bounds__(256) void lsm_k(float* __restrict__ o){
  const int row = blockIdx.x * 4 + (threadIdx.x >> 6);
  const int lane = threadIdx.x & 63;
  float* p = o + (size_t)row * NDO + lane * 4;
  float4 v = *(const float4*)p;
  float mx = fmaxf(fmaxf(v.x, v.y), fmaxf(v.z, v.w));
#pragma unroll
  for (int q = 32; q; q >>= 1) mx = fmaxf(mx, __shfl_xor(mx, q));
  float e = __expf(v.x - mx) + __expf(v.y - mx) + __expf(v.z - mx) + __expf(v.w - mx);
#pragma unroll
  for (int q = 32; q; q >>= 1) e += __shfl_xor(e, q);
  const float lse = mx + __logf(e);
  v.x -= lse; v.y -= lse; v.z -= lse; v.w -= lse;
  *(float4*)p = v;
}

// ---------------- launcher ----------------------------------------------------
extern "C" void kernel_launch(void* const* d_in, const int* in_sizes, int n_in,
                              void* d_out, int out_size, void* d_ws, size_t ws_size,
                              hipStream_t stream)
{
  (void)in_sizes; (void)n_in; (void)out_size; (void)ws_size;
  const float* x      = (const float*)d_in[0];
  const float* enc_w  = (const float*)d_in[1];
  const float* enc_b  = (const float*)d_in[2];
  const float* dec_w  = (const float*)d_in[3];
  const float* dec_b  = (const float*)d_in[4];
  const float* ln_s   = (const float*)d_in[5];
  const float* ln_b   = (const float*)d_in[6];
  const float* lam_re = (const float*)d_in[7];
  const float* lam_im = (const float*)d_in[8];
  const float* p_re   = (const float*)d_in[9];
  const float* p_im   = (const float*)d_in[10];
  const float* b_re   = (const float*)d_in[11];
  const float* b_im   = (const float*)d_in[12];
  const float* c_re   = (const float*)d_in[13];
  const float* c_im   = (const float*)d_in[14];
  const float* lstep  = (const float*)d_in[15];
  const float* d_par  = (const float*)d_in[16];
  const float* out_w  = (const float*)d_in[17];
  const float* out_b  = (const float*)d_in[18];

  char* ws = (char*)d_ws;
  u16*    hbuf = (u16*)(ws);
  u16*    zT   = (u16*)  (ws + (size_t)67108864 + 33554432);
  u16*    yT   = (u16*)  (ws + (size_t)67108864 + 2*33554432);
  float2* Kd   = (float2*)(ws + (size_t)67108864 + 3*33554432);
  u16*    Wt   = (u16*)  (ws + (size_t)67108864 + 3*33554432 + 67108864);
  u16*    WtOut = Wt + 262144;                // 4 * 512*512
  u16*    WtDec = Wt + 262144*5;              // 256*512
  float*  outp = (float*)d_out;

  // Cauchy weights live in d_out scratch (overwritten by dec gemm at the end)
  float4* cwA = (float4*)d_out;               // 131072 float4
  float4* cwB = cwA + 131072;
  float*  cwS = (float*)(cwB + 131072);

  // 1) weight prep
  prep_k<<<dim3(NLAY*DH*NST/256), 256, 0, stream>>>(lam_re, lam_im, p_re, p_im,
                                                    b_re, b_im, c_re, c_im, cwA, cwB, cwS);
  wconv_all_k<<<dim3(8, 8, 6), 256, 0, stream>>>(enc_w, out_w, dec_w, Wt);
  // 2) DPLR kernels
  cauchy_k<<<dim3(4, DH, NLAY), 256, 0, stream>>>(cwA, cwB, cwS, lstep, Kd);
  kdfft_k<<<dim3(NLAY*DH), 256, 0, stream>>>(Kd);
  // 3) encoder GEMM: h = x @ enc_w + enc_b  (f32 A in, bf16 out)
  gemm_k<2,true><<<dim3(DH/128, BL/128, 1), 256, 0, stream>>>(
      x, Wt, enc_b, hbuf, BL, DH);
  // 4) layers
  for (int i = 0; i < NLAY; i++){
    lnt_k<<<dim3(SL/LTILE, NB), 256, 0, stream>>>(hbuf, ln_s + i*DH, ln_b + i*DH, zT);
    s4conv_k<<<dim3((NB/2)*DH), 256, 0, stream>>>(
        zT, Kd + (size_t)i*DH*4096, d_par + i*DH, yT);
    gemm_at_k<<<dim3(DH/128, SL/128, NB), 256, 0, stream>>>(
        yT, WtOut + (size_t)i*262144, out_b + i*DH, hbuf, hbuf, SL, DH);
  }
  // 5) decoder (bf16 A in, f32 out) + log_softmax
  gemm_k<0,false><<<dim3(NDO/128, BL/128, 1), 256, 0, stream>>>(
      hbuf, WtDec, dec_b, outp, BL, NDO);
  lsm_k<<<dim3(BL/4), 256, 0, stream>>>(outp);
}

// Round 12
// 700.623 us; speedup vs baseline: 1.1869x; 1.0094x over previous
//
#include <hip/hip_runtime.h>
#include <hip/hip_bf16.h>

// ---------------- problem constants ----------------
#define NLAY 4
#define DH   512
#define NST  64
#define NB   16
#define SL   2048
#define NDO  256
#define BL   (NB*SL)      // 32768 rows
#define KDIM 512
#define TWOPI 6.283185307179586476925287

typedef unsigned short u16;
typedef __attribute__((ext_vector_type(8))) short  short8v;   // 8 bf16 (4 VGPR) MFMA frag
typedef __attribute__((ext_vector_type(8))) unsigned short ushort8v;
typedef __attribute__((ext_vector_type(4))) float  f32x4;
typedef __attribute__((ext_vector_type(2))) unsigned int uint2v;

#define RCPF(x) __builtin_amdgcn_rcpf(x)

// ---------------- small helpers ----------------
__device__ __forceinline__ float bf2f(u16 v){
  union { unsigned u; float f; } x; x.u = ((unsigned)v) << 16; return x.f;
}
__device__ __forceinline__ u16 f2bf(float f){
  union { float f; unsigned u; } x; x.f = f;
  unsigned u = x.u;
  unsigned r = u + 0x7fffu + ((u >> 16) & 1u);   // RNE
  return (u16)(r >> 16);
}
__device__ __forceinline__ void cmulw(float& xr, float& xi, float wr, float wi){
  float tr = xr*wr - xi*wi;
  xi = fmaf(xr, wi, xi*wr);
  xr = tr;
}
__device__ __forceinline__ float gelu_fast(float v){
  const float c0 = 0.7978845608028654f;
  float u = c0 * fmaf(0.044715f, v*v*v, v);
  return v * RCPF(1.0f + __expf(-2.0f * u));
}
// async global(16B/lane) -> LDS (wave-uniform base + lane*16, HW-linear)
__device__ __forceinline__ void gload16(const void* g, void* l){
  __builtin_amdgcn_global_load_lds(
      (__attribute__((address_space(1))) void*)(g),
      (__attribute__((address_space(3))) void*)(l), 16, 0, 0);
}

// apply w^k twiddles (w = e^{i a}) to slots k=1..15 via power recurrence:
// one hw sincos + 14 full-rate complex muls instead of 30 quarter-rate trans.
__device__ __forceinline__ void twapply(float* re, float* im, float a){
  float ci, cr;
  __sincosf(a, &ci, &cr);
  float wr = cr, wi = ci;
#pragma unroll
  for (int k = 1; k < 16; k++){
    cmulw(re[k], im[k], wr, wi);
    const float nr = wr*cr - wi*ci;
    wi = fmaf(wr, ci, wi*cr);
    wr = nr;
  }
}

// ---------------- DFT-16 in registers (radix-4 x radix-4), natural in/out ----
template<int SGN>
__device__ __forceinline__ void dft4w(float& r0, float& i0, float& r1, float& i1,
                                      float& r2, float& i2, float& r3, float& i3){
  const float t0r = r0 + r2, t0i = i0 + i2;
  const float t1r = r0 - r2, t1i = i0 - i2;
  const float t2r = r1 + r3, t2i = i1 + i3;
  const float t3r = r1 - r3, t3i = i1 - i3;
  r0 = t0r + t2r; i0 = t0i + t2i;
  r2 = t0r - t2r; i2 = t0i - t2i;
  if (SGN < 0){ r1 = t1r + t3i; i1 = t1i - t3r; r3 = t1r - t3i; i3 = t1i + t3r; }
  else        { r1 = t1r - t3i; i1 = t1i + t3r; r3 = t1r + t3i; i3 = t1i - t3r; }
}

template<int SGN>
__device__ __forceinline__ void dft16tail(float* re, float* im){
  const float C1 = 0.92387953251128675613f, S1_ = 0.38268343236508977172f;
  const float C2 = 0.70710678118654752440f;
  const float sg = (SGN < 0) ? -1.f : 1.f;
  cmulw(re[5],  im[5],   C1,  sg*S1_);
  cmulw(re[9],  im[9],   C2,  sg*C2);
  cmulw(re[13], im[13],  S1_, sg*C1);
  cmulw(re[6],  im[6],   C2,  sg*C2);
  cmulw(re[10], im[10],  0.f, sg*1.f);
  cmulw(re[14], im[14], -C2,  sg*C2);
  cmulw(re[7],  im[7],   S1_, sg*C1);
  cmulw(re[11], im[11], -C2,  sg*C2);
  cmulw(re[15], im[15], -C1,  sg*(-S1_));
#pragma unroll
  for (int c = 0; c < 4; c++)
    dft4w<SGN>(re[4*c], im[4*c], re[4*c+1], im[4*c+1], re[4*c+2], im[4*c+2], re[4*c+3], im[4*c+3]);
  float tr_, ti_;
#define SWP(A,B) tr_=re[A]; re[A]=re[B]; re[B]=tr_; ti_=im[A]; im[A]=im[B]; im[B]=ti_;
  SWP(1,4) SWP(2,8) SWP(3,12) SWP(6,9) SWP(7,13) SWP(11,14)
#undef SWP
}

template<int SGN>
__device__ __forceinline__ void dft16(float* re, float* im){
#pragma unroll
  for (int b = 0; b < 4; b++)
    dft4w<SGN>(re[b], im[b], re[4+b], im[4+b], re[8+b], im[8+b], re[12+b], im[12+b]);
  dft16tail<SGN>(re, im);
}

// forward DFT-16 with inputs 8..15 known ZERO (stage-1 butterflies degenerate)
__device__ __forceinline__ void dft16fh(float* re, float* im){
#pragma unroll
  for (int b = 0; b < 4; b++){
    const float r0 = re[b], i0 = im[b], r1 = re[4+b], i1 = im[4+b];
    re[b]    = r0 + r1; im[b]    = i0 + i1;
    re[4+b]  = r0 + i1; im[4+b]  = i0 - r1;
    re[8+b]  = r0 - r1; im[8+b]  = i0 - i1;
    re[12+b] = r0 - i1; im[12+b] = i0 + r1;
  }
  dft16tail<-1>(re, im);
}

// LDS padding: all three stage patterns <=2-way bank conflicts
__device__ __forceinline__ int cxpad(int i){ return i + (i >> 4) + ((i >> 8) << 1); }
#define CXSZ 4384

// forward 4096-pt DIF radix-16 (float2 LDS, 2 barriers total).
// Inputs slots 8..15 must be ZERO (both callers zero-pad).
__device__ __forceinline__ void fwd4096(float* re, float* im, float2* cx, int t){
  dft16fh(re, im);
  twapply(re, im, -(float)(TWOPI/4096.0) * (float)t);
#pragma unroll
  for (int k = 0; k < 16; k++) cx[cxpad(t + 256*k)] = make_float2(re[k], im[k]);
  __syncthreads();
  const int k1 = t >> 4, m2 = t & 15;
  const int b2 = k1*256 + m2;
#pragma unroll
  for (int j = 0; j < 16; j++){ float2 v = cx[cxpad(b2 + 16*j)]; re[j] = v.x; im[j] = v.y; }
  dft16<-1>(re, im);
  twapply(re, im, -(float)(TWOPI/256.0) * (float)m2);
#pragma unroll
  for (int k = 0; k < 16; k++) cx[cxpad(b2 + 16*k)] = make_float2(re[k], im[k]);
  __syncthreads();
#pragma unroll
  for (int j = 0; j < 16; j++){ float2 v = cx[cxpad(16*t + j)]; re[j] = v.x; im[j] = v.y; }
  dft16<-1>(re, im);
}

// inverse: input = values at positions 16t+k3, output time y[t+256j] (unscaled)
__device__ __forceinline__ void inv4096(float* re, float* im, float2* cx, int t){
  dft16<1>(re, im);
#pragma unroll
  for (int j = 0; j < 16; j++) cx[cxpad(16*t + j)] = make_float2(re[j], im[j]);
  __syncthreads();
  const int k1 = t >> 4, m2 = t & 15;
  const int b2 = k1*256 + m2;
#pragma unroll
  for (int k = 0; k < 16; k++){ float2 v = cx[cxpad(b2 + 16*k)]; re[k] = v.x; im[k] = v.y; }
  twapply(re, im, (float)(TWOPI/256.0) * (float)m2);
  dft16<1>(re, im);
#pragma unroll
  for (int j = 0; j < 16; j++) cx[cxpad(b2 + 16*j)] = make_float2(re[j], im[j]);
  __syncthreads();
#pragma unroll
  for (int k = 0; k < 16; k++){ float2 v = cx[cxpad(t + 256*k)]; re[k] = v.x; im[k] = v.y; }
  twapply(re, im, (float)(TWOPI/4096.0) * (float)t);
  dft16<1>(re, im);
}

// ---------------- prep: per-(lay,h,n) Woodbury weights ----------------
__global__ __launch_bounds__(256) void prep_k(
  const float* __restrict__ lam_re, const float* __restrict__ lam_im,
  const float* __restrict__ p_re,  const float* __restrict__ p_im,
  const float* __restrict__ b_re,  const float* __restrict__ b_im,
  const float* __restrict__ c_re,  const float* __restrict__ c_im,
  float4* __restrict__ cwA, float4* __restrict__ cwB, float* __restrict__ cwS)
{
  const int i = blockIdx.x * 256 + threadIdx.x;   // < NLAY*DH*NST
  const float lr = lam_re[i], li = lam_im[i];
  const float pr = p_re[i],  pi = p_im[i];
  const float br = b_re[i],  bi = b_im[i];
  const float cr = c_re[i],  ci = c_im[i];
  cwA[i] = make_float4(lr, li, cr*br + ci*bi, cr*bi - ci*br);                  // Lam, conj(C)*B
  cwB[i] = make_float4(cr*pr + ci*pi, cr*pi - ci*pr, pr*br + pi*bi, pr*bi - pi*br); // cC*P, cP*B
  cwS[i] = pr*pr + pi*pi;                                                      // conj(P)*P (real)
}

// ---------------- Cauchy/Woodbury generating function -> at_roots -----------
// g = i*gi with gi = (2/step)*tan(theta/2);  c = 1 + i*tan(theta/2).
// 2 freqs per thread (lb, lb+1024). Near its VALU floor (~122 us) — frozen.
__global__ __launch_bounds__(256) void cauchy_k(
    const float4* __restrict__ cwA, const float4* __restrict__ cwB,
    const float* __restrict__ cwS, const float* __restrict__ lstep,
    float2* __restrict__ Kd)
{
  const int t = threadIdx.x;
  const int h = blockIdx.y, lay = blockIdx.z;
  const int lb = blockIdx.x * 256 + t;           // [0, 1024)
  const int wb = (lay*DH + h) * NST;
  const float tw0 = 2.0f * expf(-lstep[lay*DH + h]);   // 2/step

  float T0,T1, g0,g1;
  { float sn, cs;
    sincosf((float)(TWOPI/4096.0)*(float)(lb       ), &sn, &cs); T0 = sn*RCPF(cs); g0 = tw0*T0;
    sincosf((float)(TWOPI/4096.0)*(float)(lb + 1024), &sn, &cs); T1 = sn*RCPF(cs); g1 = tw0*T1;
  }

  float k00r0=0,k00i0=0,k01r0=0,k01i0=0,k10r0=0,k10i0=0,k11r0=0,k11i0=0;
  float k00r1=0,k00i1=0,k01r1=0,k01i1=0,k10r1=0,k10i1=0,k11r1=0,k11i1=0;

#pragma unroll 2
  for (int n = 0; n < NST; n++){
    const float4 A  = cwA[wb + n];
    const float4 Bv = cwB[wb + n];
    const float w11 = cwS[wb + n];
    const float nlr = -A.x;            // -lam_re  (real part of g - Lam)
    const float dr2 = A.x * A.x;
#define CSTEP(J) { \
    const float di = g##J - A.y; \
    const float sI = RCPF(fmaf(di, di, dr2)); \
    const float ivr = nlr * sI, ivi = -di * sI; \
    k00r##J = fmaf(A.z,  ivr, fmaf(-A.w,  ivi, k00r##J)); \
    k00i##J = fmaf(A.z,  ivi, fmaf( A.w,  ivr, k00i##J)); \
    k01r##J = fmaf(Bv.x, ivr, fmaf(-Bv.y, ivi, k01r##J)); \
    k01i##J = fmaf(Bv.x, ivi, fmaf( Bv.y, ivr, k01i##J)); \
    k10r##J = fmaf(Bv.z, ivr, fmaf(-Bv.w, ivi, k10r##J)); \
    k10i##J = fmaf(Bv.z, ivi, fmaf( Bv.w, ivr, k10i##J)); \
    k11r##J = fmaf(w11,  ivr, k11r##J); \
    k11i##J = fmaf(w11,  ivi, k11i##J); }
    CSTEP(0) CSTEP(1)
#undef CSTEP
  }

  float2* kp = Kd + (size_t)(lay*DH + h) * 4096;
#define COUT(J, LOFF) { \
    const float d1r = 1.f + k11r##J, d1i = k11i##J; \
    const float idn = RCPF(fmaf(d1r, d1r, d1i*d1i)); \
    const float wr = k01r##J*k10r##J - k01i##J*k10i##J; \
    const float wi = k01r##J*k10i##J + k01i##J*k10r##J; \
    const float vr = fmaf(wr, d1r,  wi*d1i) * idn; \
    const float vi = fmaf(wi, d1r, -wr*d1i) * idn; \
    const float sr = k00r##J - vr, si = k00i##J - vi; \
    kp[lb + LOFF] = make_float2(fmaf(-T##J, si, sr), fmaf(T##J, sr, si)); }
  COUT(0, 0) COUT(1, 1024)
#undef COUT
}

// ---------------- ifft2048 + fwd fft4096 -> Kd (digit-rev order) -------------
__global__ __launch_bounds__(256) void kdfft_k(float2* __restrict__ Kd){
  __shared__ float  ar[SL], ai[SL];
  __shared__ float2 cx[CXSZ];
  const int t = threadIdx.x;
  const size_t base = (size_t)blockIdx.x * 4096;
#pragma unroll
  for (int q = 0; q < 8; q++){
    const int l = t + 256*q;
    float2 v = Kd[base + l];
    const int brv = __brev((unsigned)l) >> 21;    // 11-bit reverse
    ar[brv] = v.x; ai[brv] = v.y;
  }
  __syncthreads();

  // inverse DFT-2048 (radix-2 DIT, bit-reversed input -> natural K)
  for (int s = 0; s < 11; s++){
    const int half = 1 << s;
    const float fac = (float)(TWOPI) / (float)(2 << s);
#pragma unroll
    for (int q = 0; q < 4; q++){
      const int v = t + 256*q;
      const int pos = v & (half - 1);
      const int i0 = ((v >> s) << (s+1)) + pos;
      const int i1 = i0 + half;
      const float ang = fac * (float)pos;
      const float wc = __cosf(ang), ws = __sinf(ang);   // e^{+i ang}
      const float xr = ar[i1], xi = ai[i1];
      const float tr = wc*xr - ws*xi, ti = fmaf(wc, xi, ws*xr);
      const float ur_ = ar[i0], ui_ = ai[i0];
      ar[i0] = ur_ + tr; ai[i0] = ui_ + ti;
      ar[i1] = ur_ - tr; ai[i1] = ui_ - ti;
    }
    __syncthreads();
  }

  // K (real, scaled 1/2048), zero-pad to 4096, forward DIF -> Kd
  float re[16], im[16];
#pragma unroll
  for (int j = 0; j < 16; j++){
    re[j] = (j < 8) ? ar[t + 256*j] * (1.0f/2048.f) : 0.f;
    im[j] = 0.f;
  }
  fwd4096(re, im, cx, t);
  float2* kp = Kd + base + 16*t;
#pragma unroll
  for (int k = 0; k < 16; k += 2)
    *(float4*)(kp + k) = make_float4(re[k], im[k], re[k+1], im[k+1]);
}

// ---------------- weight convert+transpose f32[K][N] -> bf16[N][K] -----------
// one launch: z=0 enc, z=1..4 out_w layers, z=5 dec (y<4 only).
__global__ __launch_bounds__(256) void wconv_all_k(
    const float* __restrict__ enc_w, const float* __restrict__ out_w,
    const float* __restrict__ dec_w, u16* __restrict__ Wt)
{
  const int z = blockIdx.z;
  const float* src; u16* dst; int N;
  if (z == 0){ src = enc_w; dst = Wt; N = DH; }
  else if (z <= 4){ src = out_w + (size_t)(z-1)*KDIM*DH; dst = Wt + (size_t)z*262144; N = DH; }
  else { if (blockIdx.y >= 4) return; src = dec_w; dst = Wt + (size_t)5*262144; N = NDO; }
  __shared__ u16 tile[64][72];
  const int k0 = blockIdx.x * 64, n0 = blockIdx.y * 64;
  const int r = threadIdx.x >> 2, c4 = (threadIdx.x & 3) * 16;
  const float* s = src + (size_t)(k0 + r) * N + n0 + c4;
  float4 f0 = *(const float4*)s, f1 = *(const float4*)(s+4);
  float4 f2 = *(const float4*)(s+8), f3 = *(const float4*)(s+12);
  tile[c4+0][r]=f2bf(f0.x); tile[c4+1][r]=f2bf(f0.y); tile[c4+2][r]=f2bf(f0.z); tile[c4+3][r]=f2bf(f0.w);
  tile[c4+4][r]=f2bf(f1.x); tile[c4+5][r]=f2bf(f1.y); tile[c4+6][r]=f2bf(f1.z); tile[c4+7][r]=f2bf(f1.w);
  tile[c4+8][r]=f2bf(f2.x); tile[c4+9][r]=f2bf(f2.y); tile[c4+10][r]=f2bf(f2.z); tile[c4+11][r]=f2bf(f2.w);
  tile[c4+12][r]=f2bf(f3.x); tile[c4+13][r]=f2bf(f3.y); tile[c4+14][r]=f2bf(f3.z); tile[c4+15][r]=f2bf(f3.w);
  __syncthreads();
  u16* d = dst + (size_t)(n0 + r) * KDIM + k0 + c4;
  *(ushort8v*)d       = *(const ushort8v*)&tile[r][c4];
  *(ushort8v*)(d + 8) = *(const ushort8v*)&tile[r][c4 + 8];
}

// ---------------- fused LayerNorm + transpose: bf16 [b,l,h] -> bf16 [b,h,l] --
#define LTILE 32
__device__ __forceinline__ int lnswz(int h){ return ((h >> 1) + (h >> 6)) & 3; }

__global__ __launch_bounds__(256) void lnt_k(const u16* __restrict__ hsrc,
    const float* __restrict__ gam, const float* __restrict__ bet,
    u16* __restrict__ zT){
  __shared__ u16 tile[DH][LTILE];
  __shared__ float smu[LTILE], srs[LTILE];
  const int t = threadIdx.x;
  const int b = blockIdx.y, l0 = blockIdx.x * LTILE;
  const int r = t >> 3, hb = (t & 7) * 64;
  const u16* p = hsrc + ((size_t)b * SL + l0 + r) * DH + hb;
  float s = 0.f, sq = 0.f;
#pragma unroll
  for (int j8 = 0; j8 < 8; j8++){
    ushort8v w = *(const ushort8v*)(p + j8*8);
    const int h0 = hb + j8*8;
#pragma unroll
    for (int d = 0; d < 8; d++){
      const float f = bf2f((u16)w[d]);
      s += f; sq = fmaf(f, f, sq);
      tile[h0+d][r ^ (lnswz(h0+d) << 3)] = (u16)w[d];
    }
  }
  s  += __shfl_xor(s, 1);  sq += __shfl_xor(sq, 1);
  s  += __shfl_xor(s, 2);  sq += __shfl_xor(sq, 2);
  s  += __shfl_xor(s, 4);  sq += __shfl_xor(sq, 4);
  if ((t & 7) == 0){
    const float mu = s * (1.0f/DH);
    smu[r] = mu;
    srs[r] = rsqrtf(sq * (1.0f/DH) - mu*mu + 1e-6f);
  }
  __syncthreads();

#pragma unroll
  for (int hh = 0; hh < 2; hh++){
    const int h = t + hh*256;
    const float g = gam[h], be = bet[h];
    const int sw = lnswz(h);
    u16* dst = zT + ((size_t)b * DH + h) * SL + l0;
#pragma unroll
    for (int og = 0; og < 4; og++){
      const int lg = og ^ sw;
      ushort8v v = *(const ushort8v*)&tile[h][og*8];
      const float4 m0 = *(const float4*)&smu[lg*8];
      const float4 m1 = *(const float4*)&smu[lg*8 + 4];
      const float4 r0 = *(const float4*)&srs[lg*8];
      const float4 r1 = *(const float4*)&srs[lg*8 + 4];
      ushort8v o;
      o[0] = f2bf(fmaf(bf2f((u16)v[0]) - m0.x, r0.x*g, be));
      o[1] = f2bf(fmaf(bf2f((u16)v[1]) - m0.y, r0.y*g, be));
      o[2] = f2bf(fmaf(bf2f((u16)v[2]) - m0.z, r0.z*g, be));
      o[3] = f2bf(fmaf(bf2f((u16)v[3]) - m0.w, r0.w*g, be));
      o[4] = f2bf(fmaf(bf2f((u16)v[4]) - m1.x, r1.x*g, be));
      o[5] = f2bf(fmaf(bf2f((u16)v[5]) - m1.y, r1.y*g, be));
      o[6] = f2bf(fmaf(bf2f((u16)v[6]) - m1.z, r1.z*g, be));
      o[7] = f2bf(fmaf(bf2f((u16)v[7]) - m1.w, r1.w*g, be));
      *(ushort8v*)(dst + lg*8) = o;
    }
  }
}

// ---------------- S4 FFT convolution + D*u + GELU ----------------------------
__global__ __launch_bounds__(256) void s4conv_k(
    const u16* __restrict__ zT, const float2* __restrict__ Kd,
    const float* __restrict__ dpar, u16* __restrict__ yT)
{
  __shared__ float2 cx[CXSZ];
  const int t = threadIdx.x;
  const int wg = blockIdx.x;          // 8 pairs * 512 channels
  const int h = wg & 511, bp = wg >> 9;
  const u16* r1 = zT + ((size_t)(2*bp) * DH + h) * SL;
  const u16* r2 = r1 + (size_t)DH * SL;
  float ur1[8], ur2[8];
  float re[16], im[16];
#pragma unroll
  for (int j = 0; j < 8; j++){
    ur1[j] = bf2f(r1[t + 256*j]);
    ur2[j] = bf2f(r2[t + 256*j]);
    re[j] = ur1[j]; im[j] = ur2[j];
  }
#pragma unroll
  for (int j = 8; j < 16; j++){ re[j] = 0.f; im[j] = 0.f; }

  fwd4096(re, im, cx, t);

  const float2* kp = Kd + (size_t)h * 4096 + 16*t;
#pragma unroll
  for (int k = 0; k < 16; k += 2){
    float4 w2 = *(const float4*)(kp + k);
    cmulw(re[k],   im[k],   w2.x, w2.y);
    cmulw(re[k+1], im[k+1], w2.z, w2.w);
  }

  inv4096(re, im, cx, t);

  const float Dv = dpar[h];
  u16* y1 = yT + ((size_t)(2*bp) * DH + h) * SL;
  u16* y2 = y1 + (size_t)DH * SL;
#pragma unroll
  for (int j = 0; j < 8; j++){
    float v1 = fmaf(re[j], (1.0f/4096.f), Dv * ur1[j]);
    float v2 = fmaf(im[j], (1.0f/4096.f), Dv * ur2[j]);
    y1[t + 256*j] = f2bf(gelu_fast(v1));
    y2[t + 256*j] = f2bf(gelu_fast(v2));
  }
}

// ---------------- layer GEMM: A = yT bf16 [K][M] batched ---------------------
// A-tile: gload_lds into linear LDS arranged as 64 subtiles of 4k x 16m
// (subtile order s = mb*8 + (kb&1)*4 + (kb>>1)); the transpose-to-fragment is
// done by ds_read_b64_tr_b16 (lane l gets col l&15, rows of window (l>>4)).
// B-tile: granule layout G(r,g) = (r<<2)|((g^r^(r>>2))&3), gload_lds.
__global__ __launch_bounds__(256) void gemm_at_k(
    const u16* __restrict__ A, const u16* __restrict__ Wt,
    const float* __restrict__ bias,
    const u16* __restrict__ resid, u16* __restrict__ Cout,
    int Mb, int N)
{
  __shared__ u16 As[4096];   // 8KB: 64 subtiles x 128B
  __shared__ u16 Bs[4096];
  const int t = threadIdx.x;
  const int n0 = blockIdx.x * 128, m0 = blockIdx.y * 128, bb = blockIdx.z;
  const int lane = t & 63, wv = t >> 6;
  const int wm = (wv >> 1) * 64, wn = (wv & 1) * 64;
  const int wbase = t & 192;
  f32x4 acc[4][4];
#pragma unroll
  for (int mi = 0; mi < 4; mi++)
#pragma unroll
    for (int ni = 0; ni < 4; ni++) acc[mi][ni] = {0.f, 0.f, 0.f, 0.f};

  // decode per-thread A-source (k,m) for its 2 granules (G = t, 256+t)
  int kA[2], mA[2];
#pragma unroll
  for (int i = 0; i < 2; i++){
    const int G = i*256 + t;
    const int s = G >> 3, r8 = G & 7;
    const int q = s & 7;
    const int kb = ((q & 3) << 1) | (q >> 2);
    kA[i] = kb*4 + (r8 >> 1);
    mA[i] = (s >> 3)*16 + (r8 & 1)*8;
  }
  const size_t Abase = (size_t)bb * DH * (size_t)Mb;   // yT [b][k=h][m=l]
  const unsigned lds_as =
      (unsigned)(unsigned long long)(__attribute__((address_space(3))) u16*)As;

  for (int k0 = 0; k0 < KDIM; k0 += 32){
    __syncthreads();
#pragma unroll
    for (int i = 0; i < 2; i++)
      gload16(A + Abase + (size_t)(k0 + kA[i]) * Mb + m0 + mA[i],
              As + (size_t)(i*256 + wbase) * 8);
#pragma unroll
    for (int i = 0; i < 2; i++){
      const int G = i*256 + t;
      const int r = G >> 2;
      const int g = ((G & 3) ^ r ^ (r >> 2)) & 3;
      gload16(Wt + (size_t)(n0 + r) * KDIM + k0 + g*8,
              Bs + (size_t)(i*256 + wbase) * 8);
    }
    __syncthreads();

    // A fragments via hardware transpose read
    uint2v ra[4], rb[4];
#pragma unroll
    for (int mi = 0; mi < 4; mi++){
      const unsigned b = lds_as + (unsigned)(((wm >> 4) + mi) * 1024 + lane * 8);
      asm volatile("ds_read_b64_tr_b16 %0, %1" : "=v"(ra[mi]) : "v"(b));
      asm volatile("ds_read_b64_tr_b16 %0, %1 offset:512" : "=v"(rb[mi]) : "v"(b));
    }
    asm volatile("s_waitcnt lgkmcnt(0)" ::: "memory");
    __builtin_amdgcn_sched_barrier(0);

    short8v af[4], bf[4];
#pragma unroll
    for (int mi = 0; mi < 4; mi++){
      union { uint2v u2[2]; short8v s8; } cvt;
      cvt.u2[0] = ra[mi]; cvt.u2[1] = rb[mi];
      af[mi] = cvt.s8;
    }
    const int fr = lane & 15, g4 = lane >> 4;
#pragma unroll
    for (int ni = 0; ni < 4; ni++){
      const int r = wn + ni*16 + fr;
      bf[ni] = *(const short8v*)&Bs[(size_t)((r<<2) | ((g4 ^ r ^ (r>>2)) & 3)) * 8];
    }
#pragma unroll
    for (int mi = 0; mi < 4; mi++)
#pragma unroll
      for (int ni = 0; ni < 4; ni++)
        acc[mi][ni] = __builtin_amdgcn_mfma_f32_16x16x32_bf16(af[mi], bf[ni], acc[mi][ni], 0, 0, 0);
  }

  const int fr = lane & 15;
  const int rq = (lane >> 4) * 4;
#pragma unroll
  for (int mi = 0; mi < 4; mi++){
#pragma unroll
    for (int ni = 0; ni < 4; ni++){
      const int gn = n0 + wn + ni*16 + fr;
      const float bs = bias[gn];
#pragma unroll
      for (int q = 0; q < 4; q++){
        const int gm = m0 + wm + mi*16 + rq + q;
        const size_t idx = ((size_t)bb * Mb + gm) * N + gn;
        Cout[idx] = f2bf(acc[mi][ni][q] + bs + bf2f(resid[idx]));
      }
    }
  }
}

// ---------------- enc GEMM: granule layout, f32 A reg-convert ----------------
__global__ __launch_bounds__(256) void gemm_enc_k(
    const float* __restrict__ Af, const u16* __restrict__ Wt,
    const float* __restrict__ bias, u16* __restrict__ Cout,
    int Mb, int N)
{
  __shared__ u16 As[4096];   // 512 granules
  __shared__ u16 Bs[4096];
  const int t = threadIdx.x;
  const int n0 = blockIdx.x * 128, m0 = blockIdx.y * 128;
  const int lane = t & 63, wv = t >> 6;
  const int wm = (wv >> 1) * 64, wn = (wv & 1) * 64;
  const int wbase = t & 192;           // wave granule base
  f32x4 acc[4][4];
#pragma unroll
  for (int mi = 0; mi < 4; mi++)
#pragma unroll
    for (int ni = 0; ni < 4; ni++) acc[mi][ni] = {0.f, 0.f, 0.f, 0.f};

  for (int k0 = 0; k0 < KDIM; k0 += 32){
    __syncthreads();
    {
      const int r = t >> 1, kh = (t & 1) << 4;
      const float* sf = Af + (size_t)(m0 + r) * KDIM + k0 + kh;
      float4 f0 = *(const float4*)sf,     f1 = *(const float4*)(sf + 4);
      float4 f2 = *(const float4*)(sf+8), f3 = *(const float4*)(sf + 12);
      ushort8v v0, v1;
      v0[0]=f2bf(f0.x); v0[1]=f2bf(f0.y); v0[2]=f2bf(f0.z); v0[3]=f2bf(f0.w);
      v0[4]=f2bf(f1.x); v0[5]=f2bf(f1.y); v0[6]=f2bf(f1.z); v0[7]=f2bf(f1.w);
      v1[0]=f2bf(f2.x); v1[1]=f2bf(f2.y); v1[2]=f2bf(f2.z); v1[3]=f2bf(f2.w);
      v1[4]=f2bf(f3.x); v1[5]=f2bf(f3.y); v1[6]=f2bf(f3.z); v1[7]=f2bf(f3.w);
      const int key = (r ^ (r >> 2)) & 3;
      *(ushort8v*)&As[(size_t)((r<<2) | ((kh>>3) ^ key))*8]       = v0;
      *(ushort8v*)&As[(size_t)((r<<2) | (((kh>>3)+1) ^ key))*8]   = v1;
    }
#pragma unroll
    for (int i = 0; i < 2; i++){
      const int G = i*256 + t;
      const int r = G >> 2;
      const int g = ((G & 3) ^ r ^ (r >> 2)) & 3;
      gload16(Wt + (size_t)(n0 + r) * KDIM + k0 + g*8,
              Bs + (size_t)(i*256 + wbase) * 8);
    }
    __syncthreads();

    const int fr = lane & 15, g4 = lane >> 4;
    short8v af[4], bf[4];
#pragma unroll
    for (int mi = 0; mi < 4; mi++){
      const int r = wm + mi*16 + fr;
      af[mi] = *(const short8v*)&As[(size_t)((r<<2) | ((g4 ^ r ^ (r>>2)) & 3)) * 8];
    }
#pragma unroll
    for (int ni = 0; ni < 4; ni++){
      const int r = wn + ni*16 + fr;
      bf[ni] = *(const short8v*)&Bs[(size_t)((r<<2) | ((g4 ^ r ^ (r>>2)) & 3)) * 8];
    }
#pragma unroll
    for (int mi = 0; mi < 4; mi++)
#pragma unroll
      for (int ni = 0; ni < 4; ni++)
        acc[mi][ni] = __builtin_amdgcn_mfma_f32_16x16x32_bf16(af[mi], bf[ni], acc[mi][ni], 0, 0, 0);
  }

  const int fr = lane & 15;
  const int rq = (lane >> 4) * 4;
#pragma unroll
  for (int mi = 0; mi < 4; mi++){
#pragma unroll
    for (int ni = 0; ni < 4; ni++){
      const int gn = n0 + wn + ni*16 + fr;
      const float bs = bias[gn];
#pragma unroll
      for (int q = 0; q < 4; q++){
        const int gm = m0 + wm + mi*16 + rq + q;
        Cout[(size_t)gm * N + gn] = f2bf(acc[mi][ni][q] + bs);
      }
    }
  }
}

// ---------------- decoder GEMM (128m x 256n) + fused log-softmax -------------
// Each wave owns 32 full rows (all 256 n). Row values live on the 16 lanes
// sharing lane>>4 -> softmax reduce via 4-step shfl_xor within the group.
__global__ __launch_bounds__(256) void gemm_dec_k(
    const u16* __restrict__ A, const u16* __restrict__ Wt,
    const float* __restrict__ bias, float* __restrict__ Out)
{
  __shared__ u16 As[4096];    // 128 x 32 (512 granules)
  __shared__ u16 Bs[8192];    // 256 x 32 (1024 granules)
  const int t = threadIdx.x;
  const int m0 = blockIdx.x * 128;
  const int lane = t & 63, wv = t >> 6;
  const int wm = wv * 32;
  const int wbase = t & 192;
  f32x4 acc[2][16];
#pragma unroll
  for (int mi = 0; mi < 2; mi++)
#pragma unroll
    for (int ni = 0; ni < 16; ni++) acc[mi][ni] = {0.f, 0.f, 0.f, 0.f};

  for (int k0 = 0; k0 < KDIM; k0 += 32){
    __syncthreads();
#pragma unroll
    for (int i = 0; i < 2; i++){
      const int G = i*256 + t;
      const int r = G >> 2;
      const int g = ((G & 3) ^ r ^ (r >> 2)) & 3;
      gload16(A + (size_t)(m0 + r) * KDIM + k0 + g*8,
              As + (size_t)(i*256 + wbase) * 8);
    }
#pragma unroll
    for (int i = 0; i < 4; i++){
      const int G = i*256 + t;
      const int r = G >> 2;
      const int g = ((G & 3) ^ r ^ (r >> 2)) & 3;
      gload16(Wt + (size_t)r * KDIM + k0 + g*8,
              Bs + (size_t)(i*256 + wbase) * 8);
    }
    __syncthreads();

    const int fr = lane & 15, g4 = lane >> 4;
    short8v af[2], bf[16];
#pragma unroll
    for (int mi = 0; mi < 2; mi++){
      const int r = wm + mi*16 + fr;
      af[mi] = *(const short8v*)&As[(size_t)((r<<2) | ((g4 ^ r ^ (r>>2)) & 3)) * 8];
    }
#pragma unroll
    for (int ni = 0; ni < 16; ni++){
      const int r = ni*16 + fr;
      bf[ni] = *(const short8v*)&Bs[(size_t)((r<<2) | ((g4 ^ r ^ (r>>2)) & 3)) * 8];
    }
#pragma unroll
    for (int mi = 0; mi < 2; mi++)
#pragma unroll
      for (int ni = 0; ni < 16; ni++)
        acc[mi][ni] = __builtin_amdgcn_mfma_f32_16x16x32_bf16(af[mi], bf[ni], acc[mi][ni], 0, 0, 0);
  }

  const int fr = lane & 15, g4 = lane >> 4;
  float bssv[16];
#pragma unroll
  for (int ni = 0; ni < 16; ni++) bssv[ni] = bias[ni*16 + fr];

#pragma unroll
  for (int mi = 0; mi < 2; mi++){
#pragma unroll
    for (int q = 0; q < 4; q++){
      float v[16];
      float mx = -3.4e38f;
#pragma unroll
      for (int ni = 0; ni < 16; ni++){
        v[ni] = acc[mi][ni][q] + bssv[ni];
        mx = fmaxf(mx, v[ni]);
      }
      mx = fmaxf(mx, __shfl_xor(mx, 1));
      mx = fmaxf(mx, __shfl_xor(mx, 2));
      mx = fmaxf(mx, __shfl_xor(mx, 4));
      mx = fmaxf(mx, __shfl_xor(mx, 8));
      float e = 0.f;
#pragma unroll
      for (int ni = 0; ni < 16; ni++) e += __expf(v[ni] - mx);
      e += __shfl_xor(e, 1);
      e += __shfl_xor(e, 2);
      e += __shfl_xor(e, 4);
      e += __shfl_xor(e, 8);
      const float lse = mx + __logf(e);
      const int gm = m0 + wm + mi*16 + g4*4 + q;
      float* po = Out + (size_t)gm * NDO + fr;
#pragma unroll
      for (int ni = 0; ni < 16; ni++) po[ni*16] = v[ni] - lse;
    }
  }
}

// ---------------- launcher ----------------------------------------------------
extern "C" void kernel_launch(void* const* d_in, const int* in_sizes, int n_in,
                              void* d_out, int out_size, void* d_ws, size_t ws_size,
                              hipStream_t stream)
{
  (void)in_sizes; (void)n_in; (void)out_size; (void)ws_size;
  const float* x      = (const float*)d_in[0];
  const float* enc_w  = (const float*)d_in[1];
  const float* enc_b  = (const float*)d_in[2];
  const float* dec_w  = (const float*)d_in[3];
  const float* dec_b  = (const float*)d_in[4];
  const float* ln_s   = (const float*)d_in[5];
  const float* ln_b   = (const float*)d_in[6];
  const float* lam_re = (const float*)d_in[7];
  const float* lam_im = (const float*)d_in[8];
  const float* p_re   = (const float*)d_in[9];
  const float* p_im   = (const float*)d_in[10];
  const float* b_re   = (const float*)d_in[11];
  const float* b_im   = (const float*)d_in[12];
  const float* c_re   = (const float*)d_in[13];
  const float* c_im   = (const float*)d_in[14];
  const float* lstep  = (const float*)d_in[15];
  const float* d_par  = (const float*)d_in[16];
  const float* out_w  = (const float*)d_in[17];
  const float* out_b  = (const float*)d_in[18];

  char* ws = (char*)d_ws;
  u16*    hbuf = (u16*)(ws);
  u16*    zT   = (u16*)  (ws + (size_t)67108864 + 33554432);
  u16*    yT   = (u16*)  (ws + (size_t)67108864 + 2*33554432);
  float2* Kd   = (float2*)(ws + (size_t)67108864 + 3*33554432);
  u16*    Wt   = (u16*)  (ws + (size_t)67108864 + 3*33554432 + 67108864);
  u16*    WtOut = Wt + 262144;                // 4 * 512*512
  u16*    WtDec = Wt + 262144*5;              // 256*512
  float*  outp = (float*)d_out;

  // Cauchy weights live in d_out scratch (overwritten by dec gemm at the end)
  float4* cwA = (float4*)d_out;               // 131072 float4
  float4* cwB = cwA + 131072;
  float*  cwS = (float*)(cwB + 131072);

  // 1) weight prep
  prep_k<<<dim3(NLAY*DH*NST/256), 256, 0, stream>>>(lam_re, lam_im, p_re, p_im,
                                                    b_re, b_im, c_re, c_im, cwA, cwB, cwS);
  wconv_all_k<<<dim3(8, 8, 6), 256, 0, stream>>>(enc_w, out_w, dec_w, Wt);
  // 2) DPLR kernels
  cauchy_k<<<dim3(4, DH, NLAY), 256, 0, stream>>>(cwA, cwB, cwS, lstep, Kd);
  kdfft_k<<<dim3(NLAY*DH), 256, 0, stream>>>(Kd);
  // 3) encoder GEMM: h = x @ enc_w + enc_b  (f32 A in, bf16 out)
  gemm_enc_k<<<dim3(DH/128, BL/128, 1), 256, 0, stream>>>(
      x, Wt, enc_b, hbuf, BL, DH);
  // 4) layers
  for (int i = 0; i < NLAY; i++){
    lnt_k<<<dim3(SL/LTILE, NB), 256, 0, stream>>>(hbuf, ln_s + i*DH, ln_b + i*DH, zT);
    s4conv_k<<<dim3((NB/2)*DH), 256, 0, stream>>>(
        zT, Kd + (size_t)i*DH*4096, d_par + i*DH, yT);
    gemm_at_k<<<dim3(DH/128, SL/128, NB), 256, 0, stream>>>(
        yT, WtOut + (size_t)i*262144, out_b + i*DH, hbuf, hbuf, SL, DH);
  }
  // 5) decoder GEMM with fused log-softmax (bf16 A in, f32 out)
  gemm_dec_k<<<dim3(BL/128), 256, 0, stream>>>(hbuf, WtDec, dec_b, outp);
}